// Round 1
// baseline (686.468 us; speedup 1.0000x reference)
//
#include <hip/hip_runtime.h>
#include <hip/hip_bf16.h>

// GraphSAGE fwd on MI355X.
// Pipeline: prep weights (f32->bf16, transposed) | x->bf16 | CSR build
// (hist + 3-kernel scan + scatter) | agg1 | layer1 (MFMA, fused bias/relu/l2norm)
// | agg2 | layer2 (+fused FC head).

#define N_NODES 100000
#define N_EDGES 1600000
#define NBLK    391      // ceil(N/256)

typedef unsigned short u16;
typedef __bf16 bf16x8 __attribute__((ext_vector_type(8)));
typedef float  f32x4  __attribute__((ext_vector_type(4)));

__device__ __forceinline__ u16 f2b(float f) {
  unsigned x = __builtin_bit_cast(unsigned, f);
  unsigned r = x + 0x7fffu + ((x >> 16) & 1u);
  return (u16)(r >> 16);
}
__device__ __forceinline__ float b2f(u16 u) {
  return __builtin_bit_cast(float, (unsigned)u << 16);
}
__device__ __forceinline__ bf16x8 ldfrag(const u16* p) {
  uint4 u = *reinterpret_cast<const uint4*>(p);
  return __builtin_bit_cast(bf16x8, u);
}

// ---------------- weight prep: bf16 + transpose to [col][k] ----------------
__global__ __launch_bounds__(256) void prep_weights(
    const float* __restrict__ w1s, const float* __restrict__ w1n,
    const float* __restrict__ w2s, const float* __restrict__ w2n,
    const float* __restrict__ wfc,
    u16* __restrict__ WT1, u16* __restrict__ WT2, u16* __restrict__ WFCT) {
  int i = blockIdx.x * 256 + threadIdx.x;
  if (i < 32768) {                       // WT1: [256 cols][128 k]
    int c = i >> 7, k = i & 127;
    float v = (c < 128) ? w1s[k * 128 + c] : w1n[k * 128 + (c - 128)];
    WT1[c * 128 + k] = f2b(v);
  } else if (i < 32768 + 65536) {        // WT2: [256 cols][256 k]
    int j = i - 32768;
    int c = j >> 8, k = j & 255;
    float v = (c < 128) ? w2s[k * 128 + c] : w2n[k * 128 + (c - 128)];
    WT2[c * 256 + k] = f2b(v);
  } else {                               // WFCT: [48 cols][256 k], cols 40..47 zero
    int j = i - 98304;
    int c = j >> 8, k = j & 255;
    float v = (c < 40) ? wfc[k * 40 + c] : 0.f;
    WFCT[c * 256 + k] = f2b(v);
  }
}

// ---------------- x -> bf16 ----------------
__global__ __launch_bounds__(256) void cvt_bf16(const float* __restrict__ x,
                                                u16* __restrict__ xb) {
  size_t i = ((size_t)blockIdx.x * 256 + threadIdx.x) * 8;
  float4 a = *reinterpret_cast<const float4*>(x + i);
  float4 b = *reinterpret_cast<const float4*>(x + i + 4);
  u16 o[8] = {f2b(a.x), f2b(a.y), f2b(a.z), f2b(a.w),
              f2b(b.x), f2b(b.y), f2b(b.z), f2b(b.w)};
  *reinterpret_cast<uint4*>(xb + i) = *reinterpret_cast<const uint4*>(o);
}

// ---------------- CSR build ----------------
__global__ __launch_bounds__(256) void hist_kernel(const int* __restrict__ dst,
                                                   int* __restrict__ deg) {
  int e = blockIdx.x * 256 + threadIdx.x;
  if (e < N_EDGES) atomicAdd(&deg[dst[e]], 1);
}

__device__ __forceinline__ int wave_incl_scan(int x, int lane) {
#pragma unroll
  for (int d = 1; d < 64; d <<= 1) {
    int n = __shfl_up(x, d, 64);
    if (lane >= d) x += n;
  }
  return x;
}

__global__ __launch_bounds__(256) void k_blocksum(const int* __restrict__ deg,
                                                  int* __restrict__ bsum) {
  int i = blockIdx.x * 256 + threadIdx.x;
  int lane = threadIdx.x & 63, wid = threadIdx.x >> 6;
  int v = (i < N_NODES) ? deg[i] : 0;
#pragma unroll
  for (int d = 1; d < 64; d <<= 1) v += __shfl_xor(v, d, 64);
  __shared__ int ws[4];
  if (lane == 0) ws[wid] = v;
  __syncthreads();
  if (threadIdx.x == 0) bsum[blockIdx.x] = ws[0] + ws[1] + ws[2] + ws[3];
}

__global__ __launch_bounds__(512) void k_scanbsum(const int* __restrict__ bsum,
                                                  int* __restrict__ boff) {
  int t = threadIdx.x, lane = t & 63, wid = t >> 6;
  int v = (t < NBLK) ? bsum[t] : 0;
  int inc = wave_incl_scan(v, lane);
  __shared__ int ws[8];
  if (lane == 63) ws[wid] = inc;
  __syncthreads();
  if (wid == 0) {
    int s = (lane < 8) ? ws[lane] : 0;
    s = wave_incl_scan(s, lane);
    if (lane < 8) ws[lane] = s;
  }
  __syncthreads();
  int woff = wid ? ws[wid - 1] : 0;
  if (t < NBLK) boff[t] = woff + inc - v;
}

__global__ __launch_bounds__(256) void k_ptr(const int* __restrict__ deg,
                                             const int* __restrict__ boff,
                                             int* __restrict__ rowptr,
                                             int* __restrict__ cursor) {
  int i = blockIdx.x * 256 + threadIdx.x;
  int lane = threadIdx.x & 63, wid = threadIdx.x >> 6;
  int v = (i < N_NODES) ? deg[i] : 0;
  int inc = wave_incl_scan(v, lane);
  __shared__ int ws[4];
  if (lane == 63) ws[wid] = inc;
  __syncthreads();
  if (wid == 0) {
    int s = (lane < 4) ? ws[lane] : 0;
    s = wave_incl_scan(s, lane);
    if (lane < 4) ws[lane] = s;
  }
  __syncthreads();
  int ex = boff[blockIdx.x] + (wid ? ws[wid - 1] : 0) + inc - v;
  if (i < N_NODES) {
    rowptr[i] = ex;
    cursor[i] = ex;
    if (i == N_NODES - 1) rowptr[N_NODES] = ex + v;
  }
}

__global__ __launch_bounds__(256) void scatter_kernel(const int* __restrict__ src,
                                                      const int* __restrict__ dst,
                                                      int* __restrict__ cursor,
                                                      int* __restrict__ csr) {
  int e = blockIdx.x * 256 + threadIdx.x;
  if (e < N_EDGES) {
    int d = dst[e];
    int pos = atomicAdd(&cursor[d], 1);
    csr[pos] = src[e];
  }
}

// ---------------- mean aggregation: one wave per node ----------------
template <int C>
__device__ __forceinline__ void add_row(float* acc, const u16* __restrict__ F,
                                        int s, int lane) {
  if constexpr (C == 128) {
    ushort2 u = *reinterpret_cast<const ushort2*>(F + (size_t)s * C + lane * 2);
    acc[0] += b2f(u.x);
    acc[1] += b2f(u.y);
  } else {
    ushort4 u = *reinterpret_cast<const ushort4*>(F + (size_t)s * C + lane * 4);
    acc[0] += b2f(u.x);
    acc[1] += b2f(u.y);
    acc[2] += b2f(u.z);
    acc[3] += b2f(u.w);
  }
}

template <int C>
__global__ __launch_bounds__(256) void agg_kernel(const u16* __restrict__ F,
                                                  const int* __restrict__ rowptr,
                                                  const int* __restrict__ csr,
                                                  u16* __restrict__ O) {
  int node = (int)((blockIdx.x * 256 + threadIdx.x) >> 6);
  int lane = threadIdx.x & 63;
  if (node >= N_NODES) return;
  int beg = rowptr[node], end = rowptr[node + 1];
  constexpr int V = C / 64;
  float acc[V];
#pragma unroll
  for (int v = 0; v < V; ++v) acc[v] = 0.f;
  int j = beg;
  for (; j + 3 < end; j += 4) {
    int s0 = csr[j], s1 = csr[j + 1], s2 = csr[j + 2], s3 = csr[j + 3];
    add_row<C>(acc, F, s0, lane);
    add_row<C>(acc, F, s1, lane);
    add_row<C>(acc, F, s2, lane);
    add_row<C>(acc, F, s3, lane);
  }
  for (; j < end; ++j) add_row<C>(acc, F, csr[j], lane);
  int d = end - beg;
  float inv = 1.f / (float)(d > 0 ? d : 1);
  if constexpr (C == 128) {
    ushort2 o;
    o.x = f2b(acc[0] * inv);
    o.y = f2b(acc[1] * inv);
    *reinterpret_cast<ushort2*>(O + (size_t)node * C + lane * 2) = o;
  } else {
    ushort4 o;
    o.x = f2b(acc[0] * inv);
    o.y = f2b(acc[1] * inv);
    o.z = f2b(acc[2] * inv);
    o.w = f2b(acc[3] * inv);
    *reinterpret_cast<ushort4*>(O + (size_t)node * C + lane * 4) = o;
  }
}

// ---------------- SAGE layer: [32 rows x 256 cols] per block, 4 waves ----------------
// wave w: rt = w&1 (row tile of 16), half = w>>1 (0: self@Ws, 1: neigh@Wn).
// A-frag: row = lane&15, k = 8*(lane>>4)+j  (consistent A/B k-mapping => correct sum).
// Epilogue: bias+relu, row l2norm (shfl-xor over 16 col-lanes + LDS cross-wave),
// then either store h bf16 (layer1) or fused FC head via wfcT (layer2).
template <int K, bool FC>
__global__ __launch_bounds__(256) void layer_kernel(
    const u16* __restrict__ Aself, const u16* __restrict__ Aneigh,
    const u16* __restrict__ WT, const float* __restrict__ bs,
    const float* __restrict__ bn, u16* __restrict__ Hout,
    const u16* __restrict__ WFCT, const float* __restrict__ bfc,
    float* __restrict__ Out) {
  const int tid = threadIdx.x;
  const int w = tid >> 6, lane = tid & 63;
  const int rt = w & 1, half = w >> 1;
  const int lrow = lane & 15, lk = lane >> 4;
  const int row0 = blockIdx.x * 32 + rt * 16;

  const u16* Abase = half ? Aneigh : Aself;
  const u16* arow = Abase + (size_t)(row0 + lrow) * K + lk * 8;
  const u16* wcol = WT + (size_t)(half * 128 + lrow) * K + lk * 8;

  f32x4 acc[8];
#pragma unroll
  for (int ct = 0; ct < 8; ++ct) acc[ct] = f32x4{0.f, 0.f, 0.f, 0.f};

  for (int k0 = 0; k0 < K; k0 += 32) {
    bf16x8 a = ldfrag(arow + k0);
#pragma unroll
    for (int ct = 0; ct < 8; ++ct) {
      bf16x8 b = ldfrag(wcol + (size_t)ct * (16 * K) + k0);
      acc[ct] = __builtin_amdgcn_mfma_f32_16x16x32_bf16(a, b, acc[ct], 0, 0, 0);
    }
  }

  // bias + relu + per-row sum of squares
  float ss[4] = {0.f, 0.f, 0.f, 0.f};
#pragma unroll
  for (int ct = 0; ct < 8; ++ct) {
    int col = half * 128 + ct * 16 + lrow;
    float bv = (col < 128) ? bs[col] : bn[col - 128];
#pragma unroll
    for (int j = 0; j < 4; ++j) {
      float v = acc[ct][j] + bv;
      v = fmaxf(v, 0.f);
      acc[ct][j] = v;
      ss[j] += v * v;
    }
  }
#pragma unroll
  for (int off = 1; off < 16; off <<= 1) {
#pragma unroll
    for (int j = 0; j < 4; ++j) ss[j] += __shfl_xor(ss[j], off, 64);
  }
  __shared__ float rs[2][2][16];
  __shared__ u16 sh[32][264];  // +8 pad: conflict-free b128 row reads
  if (lrow == 0) {
#pragma unroll
    for (int j = 0; j < 4; ++j) rs[rt][half][lk * 4 + j] = ss[j];
  }
  __syncthreads();
#pragma unroll
  for (int j = 0; j < 4; ++j) {
    int r = lk * 4 + j;
    float tot = rs[rt][0][r] + rs[rt][1][r];
    float s = 1.f / fmaxf(sqrtf(tot), 1e-12f);
#pragma unroll
    for (int ct = 0; ct < 8; ++ct) {
      sh[rt * 16 + r][half * 128 + ct * 16 + lrow] = f2b(acc[ct][j] * s);
    }
  }
  __syncthreads();

  if constexpr (!FC) {
    // coalesced copy of 32 rows x 256 bf16 to global
    const uint4* shu = reinterpret_cast<const uint4*>(&sh[0][0]);
    uint4* g = reinterpret_cast<uint4*>(Hout);
    for (int i = tid; i < 1024; i += 256) {
      int r = i >> 5, c = i & 31;
      g[((size_t)blockIdx.x * 32 + r) * 32 + c] = shu[r * 33 + c];
    }
  } else {
    // fused FC head: out[32 x 40] = h2 @ wfc + bfc. wave: rt=w&1, kh=w>>1.
    const int kh = half;
    f32x4 fca[3];
#pragma unroll
    for (int c3 = 0; c3 < 3; ++c3) fca[c3] = f32x4{0.f, 0.f, 0.f, 0.f};
    const u16* shrow = &sh[rt * 16 + lrow][kh * 128];
    const u16* wf = WFCT + (size_t)lrow * 256 + kh * 128 + lk * 8;
#pragma unroll
    for (int k0 = 0; k0 < 128; k0 += 32) {
      bf16x8 a = ldfrag(shrow + k0 + lk * 8);
#pragma unroll
      for (int c3 = 0; c3 < 3; ++c3) {
        bf16x8 b = ldfrag(wf + (size_t)c3 * 16 * 256 + k0);
        fca[c3] = __builtin_amdgcn_mfma_f32_16x16x32_bf16(a, b, fca[c3], 0, 0, 0);
      }
    }
    __shared__ float sfc[2][2][16][48];  // [kh][rt][row][col]
#pragma unroll
    for (int c3 = 0; c3 < 3; ++c3) {
#pragma unroll
      for (int j = 0; j < 4; ++j) {
        sfc[kh][rt][lk * 4 + j][c3 * 16 + lrow] = fca[c3][j];
      }
    }
    __syncthreads();
    for (int i = tid; i < 32 * 40; i += 256) {
      int r = i / 40, c = i % 40;
      float v = sfc[0][r >> 4][r & 15][c] + sfc[1][r >> 4][r & 15][c] + bfc[c];
      Out[((size_t)blockIdx.x * 32 + r) * 40 + c] = v;
    }
  }
}

// ---------------- launch ----------------
extern "C" void kernel_launch(void* const* d_in, const int* in_sizes, int n_in,
                              void* d_out, int out_size, void* d_ws, size_t ws_size,
                              hipStream_t stream) {
  const float* x = (const float*)d_in[0];
  const int* src = (const int*)d_in[1];
  const int* dst = (const int*)d_in[2];
  const float* w1s = (const float*)d_in[3];
  const float* b1s = (const float*)d_in[4];
  const float* w1n = (const float*)d_in[5];
  const float* b1n = (const float*)d_in[6];
  const float* w2s = (const float*)d_in[7];
  const float* b2s = (const float*)d_in[8];
  const float* w2n = (const float*)d_in[9];
  const float* b2n = (const float*)d_in[10];
  const float* wfc = (const float*)d_in[11];
  const float* bfc = (const float*)d_in[12];
  float* out = (float*)d_out;

  char* p = (char*)d_ws;
  auto alloc = [&](size_t bytes) {
    char* r = p;
    p += (bytes + 255) & ~(size_t)255;
    return r;
  };
  u16* xb = (u16*)alloc((size_t)N_NODES * 128 * 2);   // 25.6 MB
  u16* h1b = (u16*)alloc((size_t)N_NODES * 256 * 2);  // 51.2 MB
  u16* ngb = (u16*)alloc((size_t)N_NODES * 256 * 2);  // 51.2 MB (reused both layers)
  u16* WT1 = (u16*)alloc(32768 * 2);
  u16* WT2 = (u16*)alloc(65536 * 2);
  u16* WFCT = (u16*)alloc(12288 * 2);
  int* deg = (int*)alloc(N_NODES * 4);
  int* rowptr = (int*)alloc((N_NODES + 1) * 4);
  int* cursor = (int*)alloc(N_NODES * 4);
  int* csr = (int*)alloc((size_t)N_EDGES * 4);
  int* bsum = (int*)alloc(NBLK * 4);
  int* boff = (int*)alloc(NBLK * 4);

  hipMemsetAsync(deg, 0, N_NODES * 4, stream);
  prep_weights<<<432, 256, 0, stream>>>(w1s, w1n, w2s, w2n, wfc, WT1, WT2, WFCT);
  cvt_bf16<<<6250, 256, 0, stream>>>(x, xb);
  hist_kernel<<<6250, 256, 0, stream>>>(dst, deg);
  k_blocksum<<<NBLK, 256, 0, stream>>>(deg, bsum);
  k_scanbsum<<<1, 512, 0, stream>>>(bsum, boff);
  k_ptr<<<NBLK, 256, 0, stream>>>(deg, boff, rowptr, cursor);
  scatter_kernel<<<6250, 256, 0, stream>>>(src, dst, cursor, csr);

  agg_kernel<128><<<25000, 256, 0, stream>>>(xb, rowptr, csr, ngb);
  layer_kernel<128, false><<<3125, 256, 0, stream>>>(xb, ngb, WT1, b1s, b1n, h1b,
                                                     nullptr, nullptr, nullptr);
  agg_kernel<256><<<25000, 256, 0, stream>>>(h1b, rowptr, csr, ngb);
  layer_kernel<256, true><<<3125, 256, 0, stream>>>(h1b, ngb, WT2, b2s, b2n, nullptr,
                                                    WFCT, bfc, out);
}

// Round 2
// 541.117 us; speedup vs baseline: 1.2686x; 1.2686x over previous
//
#include <hip/hip_runtime.h>
#include <hip/hip_bf16.h>

// GraphSAGE fwd on MI355X, v2.
// Key change vs v1: aggregation commuted past the matmul (mean(h[src])@Wn ==
// mean((h@Wn)[src])), so layers become pure GEMMs (LDS-resident swizzled
// weights, persistent blocks) and the gather works on 128-col rows.
// Pipeline: prep | cvt | CSR | gemm1 | agg+epi1 | gemm2 | agg+epi2 | fc.

#define N_NODES 100000
#define N_EDGES 1600000
#define NBLK    391      // ceil(N/256)

typedef unsigned short u16;
typedef __bf16 bf16x8 __attribute__((ext_vector_type(8)));
typedef float  f32x4  __attribute__((ext_vector_type(4)));

__device__ __forceinline__ u16 f2b(float f) {
  unsigned x = __builtin_bit_cast(unsigned, f);
  unsigned r = x + 0x7fffu + ((x >> 16) & 1u);
  return (u16)(r >> 16);
}
__device__ __forceinline__ float b2f(u16 u) {
  return __builtin_bit_cast(float, (unsigned)u << 16);
}
__device__ __forceinline__ bf16x8 ldfrag(const u16* p) {
  uint4 u = *reinterpret_cast<const uint4*>(p);
  return __builtin_bit_cast(bf16x8, u);
}

// ---------------- weight prep: bf16 + transpose to [col][k] ----------------
__global__ __launch_bounds__(256) void prep_weights(
    const float* __restrict__ w1s, const float* __restrict__ w1n,
    const float* __restrict__ w2s, const float* __restrict__ w2n,
    const float* __restrict__ wfc,
    u16* __restrict__ WT1, u16* __restrict__ WT2, u16* __restrict__ WFCT) {
  int i = blockIdx.x * 256 + threadIdx.x;
  if (i < 32768) {                       // WT1: [256 cols][128 k]
    int c = i >> 7, k = i & 127;
    float v = (c < 128) ? w1s[k * 128 + c] : w1n[k * 128 + (c - 128)];
    WT1[c * 128 + k] = f2b(v);
  } else if (i < 32768 + 65536) {        // WT2: [256 cols][256 k]
    int j = i - 32768;
    int c = j >> 8, k = j & 255;
    float v = (c < 128) ? w2s[k * 128 + c] : w2n[k * 128 + (c - 128)];
    WT2[c * 256 + k] = f2b(v);
  } else {                               // WFCT: [48 cols][256 k], cols 40..47 zero
    int j = i - 98304;
    int c = j >> 8, k = j & 255;
    float v = (c < 40) ? wfc[k * 40 + c] : 0.f;
    WFCT[c * 256 + k] = f2b(v);
  }
}

// ---------------- x -> bf16 ----------------
__global__ __launch_bounds__(256) void cvt_bf16(const float* __restrict__ x,
                                                u16* __restrict__ xb) {
  size_t i = ((size_t)blockIdx.x * 256 + threadIdx.x) * 8;
  float4 a = *reinterpret_cast<const float4*>(x + i);
  float4 b = *reinterpret_cast<const float4*>(x + i + 4);
  u16 o[8] = {f2b(a.x), f2b(a.y), f2b(a.z), f2b(a.w),
              f2b(b.x), f2b(b.y), f2b(b.z), f2b(b.w)};
  *reinterpret_cast<uint4*>(xb + i) = *reinterpret_cast<const uint4*>(o);
}

// ---------------- CSR build ----------------
__global__ __launch_bounds__(256) void hist_kernel(const int* __restrict__ dst,
                                                   int* __restrict__ deg) {
  int e = blockIdx.x * 256 + threadIdx.x;
  if (e < N_EDGES) atomicAdd(&deg[dst[e]], 1);
}

__device__ __forceinline__ int wave_incl_scan(int x, int lane) {
#pragma unroll
  for (int d = 1; d < 64; d <<= 1) {
    int n = __shfl_up(x, d, 64);
    if (lane >= d) x += n;
  }
  return x;
}

__global__ __launch_bounds__(256) void k_blocksum(const int* __restrict__ deg,
                                                  int* __restrict__ bsum) {
  int i = blockIdx.x * 256 + threadIdx.x;
  int lane = threadIdx.x & 63, wid = threadIdx.x >> 6;
  int v = (i < N_NODES) ? deg[i] : 0;
#pragma unroll
  for (int d = 1; d < 64; d <<= 1) v += __shfl_xor(v, d, 64);
  __shared__ int ws[4];
  if (lane == 0) ws[wid] = v;
  __syncthreads();
  if (threadIdx.x == 0) bsum[blockIdx.x] = ws[0] + ws[1] + ws[2] + ws[3];
}

__global__ __launch_bounds__(512) void k_scanbsum(const int* __restrict__ bsum,
                                                  int* __restrict__ boff) {
  int t = threadIdx.x, lane = t & 63, wid = t >> 6;
  int v = (t < NBLK) ? bsum[t] : 0;
  int inc = wave_incl_scan(v, lane);
  __shared__ int ws[8];
  if (lane == 63) ws[wid] = inc;
  __syncthreads();
  if (wid == 0) {
    int s = (lane < 8) ? ws[lane] : 0;
    s = wave_incl_scan(s, lane);
    if (lane < 8) ws[lane] = s;
  }
  __syncthreads();
  int woff = wid ? ws[wid - 1] : 0;
  if (t < NBLK) boff[t] = woff + inc - v;
}

__global__ __launch_bounds__(256) void k_ptr(const int* __restrict__ deg,
                                             const int* __restrict__ boff,
                                             int* __restrict__ rowptr,
                                             int* __restrict__ cursor) {
  int i = blockIdx.x * 256 + threadIdx.x;
  int lane = threadIdx.x & 63, wid = threadIdx.x >> 6;
  int v = (i < N_NODES) ? deg[i] : 0;
  int inc = wave_incl_scan(v, lane);
  __shared__ int ws[4];
  if (lane == 63) ws[wid] = inc;
  __syncthreads();
  if (wid == 0) {
    int s = (lane < 4) ? ws[lane] : 0;
    s = wave_incl_scan(s, lane);
    if (lane < 4) ws[lane] = s;
  }
  __syncthreads();
  int ex = boff[blockIdx.x] + (wid ? ws[wid - 1] : 0) + inc - v;
  if (i < N_NODES) {
    rowptr[i] = ex;
    cursor[i] = ex;
    if (i == N_NODES - 1) rowptr[N_NODES] = ex + v;
  }
}

__global__ __launch_bounds__(256) void scatter_kernel(const int* __restrict__ src,
                                                      const int* __restrict__ dst,
                                                      int* __restrict__ cursor,
                                                      int* __restrict__ csr) {
  int e = blockIdx.x * 256 + threadIdx.x;
  if (e < N_EDGES) {
    int d = dst[e];
    int pos = atomicAdd(&cursor[d], 1);
    csr[pos] = src[e];
  }
}

// ---------------- persistent GEMM: C[s|n] = A[N,K] @ WT ----------------
// Block: 128 rows x 128 cols (one col-half). B staged once in LDS, XOR-swizzled
// so the 16-lane column-slice ds_read_b128 is bank-balanced. Persistent over
// row-chunks (stride gridDim/2). Wave: 2 row-tiles x 8 col-tiles.
template <int K>
__global__ __launch_bounds__(256) void gemm_kernel(
    const u16* __restrict__ A, const u16* __restrict__ WT,
    u16* __restrict__ Cs, u16* __restrict__ Cn) {
  constexpr int RB = K * 2;                      // LDS bytes per col-row
  constexpr int LOG2RB = (K == 128) ? 8 : 9;
  constexpr int KS = K / 32;
  __shared__ u16 lb[128 * K];                    // 32/64 KB

  const int tid = threadIdx.x;
  const int half = blockIdx.x & 1;
  u16* __restrict__ Cout = half ? Cn : Cs;

  // stage weight half -> LDS (swizzled)
  const u16* Wsrc = WT + (size_t)half * 128 * K;
  char* lbc = reinterpret_cast<char*>(lb);
#pragma unroll
  for (int i = tid; i < 128 * K / 8; i += 256) {
    uint4 v = *reinterpret_cast<const uint4*>(Wsrc + i * 8);
    int byte = i * 16;
    int swz = byte ^ (((byte >> LOG2RB) & 7) << 4);
    *reinterpret_cast<uint4*>(lbc + swz) = v;
  }
  __syncthreads();

  const int w = tid >> 6, lane = tid & 63;
  const int lrow = lane & 15, lk = lane >> 4;
  const int xr = (lrow & 7) << 4;                // lane-constant XOR
  const int stride = gridDim.x >> 1;

  for (int chunk = blockIdx.x >> 1; chunk * 128 < N_NODES; chunk += stride) {
    const int rbase = chunk * 128 + w * 32;
    // preload all A-fragments for this chunk (independent global loads)
    bf16x8 af[2][KS];
#pragma unroll
    for (int rt = 0; rt < 2; ++rt) {
      int r = rbase + rt * 16 + lrow;
      if (r >= N_NODES) r = N_NODES - 1;
      const u16* ap = A + (size_t)r * K + lk * 8;
#pragma unroll
      for (int ks = 0; ks < KS; ++ks) af[rt][ks] = ldfrag(ap + ks * 32);
    }
    f32x4 acc[2][8];
#pragma unroll
    for (int rt = 0; rt < 2; ++rt)
#pragma unroll
      for (int ct = 0; ct < 8; ++ct) acc[rt][ct] = f32x4{0.f, 0.f, 0.f, 0.f};

#pragma unroll
    for (int ks = 0; ks < KS; ++ks) {
#pragma unroll
      for (int ct = 0; ct < 8; ++ct) {
        int byte = (ct * 16 + lrow) * RB + ks * 64 + lk * 16;
        bf16x8 b = __builtin_bit_cast(
            bf16x8, *reinterpret_cast<const uint4*>(lbc + (byte ^ xr)));
        acc[0][ct] = __builtin_amdgcn_mfma_f32_16x16x32_bf16(af[0][ks], b, acc[0][ct], 0, 0, 0);
        acc[1][ct] = __builtin_amdgcn_mfma_f32_16x16x32_bf16(af[1][ks], b, acc[1][ct], 0, 0, 0);
      }
    }
    // store (D: row = 4*lk + j, col = ct*16 + lrow)
#pragma unroll
    for (int rt = 0; rt < 2; ++rt) {
#pragma unroll
      for (int j = 0; j < 4; ++j) {
        int r = rbase + rt * 16 + lk * 4 + j;
        if (r < N_NODES) {
          u16* cp = Cout + (size_t)r * 128 + lrow;
#pragma unroll
          for (int ct = 0; ct < 8; ++ct) cp[ct * 16] = f2b(acc[rt][ct][j]);
        }
      }
    }
  }
}

// ---------------- fused mean-agg + bias/relu/l2norm epilogue ----------------
// One wave per node. Xs/Xn are [N,128] bf16 pre-bias GEMM outputs; gathers Xn
// rows of the CSR neighbors (256B, fully coalesced per wave), adds biases,
// relu, row-l2norm, writes H [N,256] bf16.
__global__ __launch_bounds__(256) void agg_epi_kernel(
    const u16* __restrict__ Xs, const u16* __restrict__ Xn,
    const int* __restrict__ rowptr, const int* __restrict__ csr,
    const float* __restrict__ bs, const float* __restrict__ bn,
    u16* __restrict__ H) {
  int node = (int)((blockIdx.x * 256 + threadIdx.x) >> 6);
  int lane = threadIdx.x & 63;
  if (node >= N_NODES) return;
  int beg = rowptr[node], end = rowptr[node + 1];
  float a0 = 0.f, a1 = 0.f;
  int j = beg;
  for (; j + 3 < end; j += 4) {
    int s0 = csr[j], s1 = csr[j + 1], s2 = csr[j + 2], s3 = csr[j + 3];
    ushort2 u0 = *reinterpret_cast<const ushort2*>(Xn + (size_t)s0 * 128 + lane * 2);
    ushort2 u1 = *reinterpret_cast<const ushort2*>(Xn + (size_t)s1 * 128 + lane * 2);
    ushort2 u2 = *reinterpret_cast<const ushort2*>(Xn + (size_t)s2 * 128 + lane * 2);
    ushort2 u3 = *reinterpret_cast<const ushort2*>(Xn + (size_t)s3 * 128 + lane * 2);
    a0 += b2f(u0.x) + b2f(u1.x) + b2f(u2.x) + b2f(u3.x);
    a1 += b2f(u0.y) + b2f(u1.y) + b2f(u2.y) + b2f(u3.y);
  }
  for (; j < end; ++j) {
    ushort2 u = *reinterpret_cast<const ushort2*>(Xn + (size_t)csr[j] * 128 + lane * 2);
    a0 += b2f(u.x);
    a1 += b2f(u.y);
  }
  int d = end - beg;
  float inv = 1.f / (float)(d > 0 ? d : 1);
  ushort2 sv = *reinterpret_cast<const ushort2*>(Xs + (size_t)node * 128 + lane * 2);
  float2 bsv = *reinterpret_cast<const float2*>(bs + lane * 2);
  float2 bnv = *reinterpret_cast<const float2*>(bn + lane * 2);
  float s0 = fmaxf(b2f(sv.x) + bsv.x, 0.f);
  float s1 = fmaxf(b2f(sv.y) + bsv.y, 0.f);
  float n0 = fmaxf(a0 * inv + bnv.x, 0.f);
  float n1 = fmaxf(a1 * inv + bnv.y, 0.f);
  float ss = s0 * s0 + s1 * s1 + n0 * n0 + n1 * n1;
#pragma unroll
  for (int off = 1; off < 64; off <<= 1) ss += __shfl_xor(ss, off, 64);
  float sc = 1.f / fmaxf(sqrtf(ss), 1e-12f);
  ushort2 o0, o1;
  o0.x = f2b(s0 * sc);
  o0.y = f2b(s1 * sc);
  o1.x = f2b(n0 * sc);
  o1.y = f2b(n1 * sc);
  *reinterpret_cast<ushort2*>(H + (size_t)node * 256 + lane * 2) = o0;
  *reinterpret_cast<ushort2*>(H + (size_t)node * 256 + 128 + lane * 2) = o1;
}

// ---------------- FC head: out[N,40] = h2 @ wfc + bfc ----------------
__global__ __launch_bounds__(256) void fc_kernel(const u16* __restrict__ H2,
                                                 const u16* __restrict__ WFCT,
                                                 const float* __restrict__ bfc,
                                                 float* __restrict__ Out) {
  __shared__ u16 lb[48 * 256];   // 24 KB, swizzled RB=512
  char* lbc = reinterpret_cast<char*>(lb);
  const int tid = threadIdx.x;
#pragma unroll
  for (int i = tid; i < 48 * 256 / 8; i += 256) {
    uint4 v = *reinterpret_cast<const uint4*>(WFCT + i * 8);
    int byte = i * 16;
    int swz = byte ^ (((byte >> 9) & 7) << 4);
    *reinterpret_cast<uint4*>(lbc + swz) = v;
  }
  __syncthreads();
  const int w = tid >> 6, lane = tid & 63;
  const int lrow = lane & 15, lk = lane >> 4;
  const int xr = (lrow & 7) << 4;
  const int rbase = blockIdx.x * 64 + w * 16;

  bf16x8 af[8];
  {
    int r = rbase + lrow;
    if (r >= N_NODES) r = N_NODES - 1;
    const u16* ap = H2 + (size_t)r * 256 + lk * 8;
#pragma unroll
    for (int ks = 0; ks < 8; ++ks) af[ks] = ldfrag(ap + ks * 32);
  }
  f32x4 acc[3];
#pragma unroll
  for (int ct = 0; ct < 3; ++ct) acc[ct] = f32x4{0.f, 0.f, 0.f, 0.f};
#pragma unroll
  for (int ks = 0; ks < 8; ++ks) {
#pragma unroll
    for (int ct = 0; ct < 3; ++ct) {
      int byte = (ct * 16 + lrow) * 512 + ks * 64 + lk * 16;
      bf16x8 b = __builtin_bit_cast(
          bf16x8, *reinterpret_cast<const uint4*>(lbc + (byte ^ xr)));
      acc[ct] = __builtin_amdgcn_mfma_f32_16x16x32_bf16(af[ks], b, acc[ct], 0, 0, 0);
    }
  }
#pragma unroll
  for (int j = 0; j < 4; ++j) {
    int r = rbase + lk * 4 + j;
    if (r < N_NODES) {
#pragma unroll
      for (int ct = 0; ct < 3; ++ct) {
        int col = ct * 16 + lrow;
        if (col < 40) Out[(size_t)r * 40 + col] = acc[ct][j] + bfc[col];
      }
    }
  }
}

// ---------------- launch ----------------
extern "C" void kernel_launch(void* const* d_in, const int* in_sizes, int n_in,
                              void* d_out, int out_size, void* d_ws, size_t ws_size,
                              hipStream_t stream) {
  const float* x = (const float*)d_in[0];
  const int* src = (const int*)d_in[1];
  const int* dst = (const int*)d_in[2];
  const float* w1s = (const float*)d_in[3];
  const float* b1s = (const float*)d_in[4];
  const float* w1n = (const float*)d_in[5];
  const float* b1n = (const float*)d_in[6];
  const float* w2s = (const float*)d_in[7];
  const float* b2s = (const float*)d_in[8];
  const float* w2n = (const float*)d_in[9];
  const float* b2n = (const float*)d_in[10];
  const float* wfc = (const float*)d_in[11];
  const float* bfc = (const float*)d_in[12];
  float* out = (float*)d_out;

  char* p = (char*)d_ws;
  auto alloc = [&](size_t bytes) {
    char* r = p;
    p += (bytes + 255) & ~(size_t)255;
    return r;
  };
  u16* xb = (u16*)alloc((size_t)N_NODES * 128 * 2);   // 25.6 MB
  u16* XWs = (u16*)alloc((size_t)N_NODES * 128 * 2);  // 25.6 MB (reused L1/L2)
  u16* XWn = (u16*)alloc((size_t)N_NODES * 128 * 2);  // 25.6 MB (reused L1/L2)
  u16* h1 = (u16*)alloc((size_t)N_NODES * 256 * 2);   // 51.2 MB (h2 aliases)
  u16* WT1 = (u16*)alloc(32768 * 2);
  u16* WT2 = (u16*)alloc(65536 * 2);
  u16* WFCT = (u16*)alloc(12288 * 2);
  int* deg = (int*)alloc(N_NODES * 4);
  int* rowptr = (int*)alloc((N_NODES + 1) * 4);
  int* cursor = (int*)alloc(N_NODES * 4);
  int* csr = (int*)alloc((size_t)N_EDGES * 4);
  int* bsum = (int*)alloc(NBLK * 4);
  int* boff = (int*)alloc(NBLK * 4);
  u16* h2 = h1;  // h1 dead after gemm2; agg2 writes h2 into the same buffer

  hipMemsetAsync(deg, 0, N_NODES * 4, stream);
  prep_weights<<<432, 256, 0, stream>>>(w1s, w1n, w2s, w2n, wfc, WT1, WT2, WFCT);
  cvt_bf16<<<6250, 256, 0, stream>>>(x, xb);
  hist_kernel<<<6250, 256, 0, stream>>>(dst, deg);
  k_blocksum<<<NBLK, 256, 0, stream>>>(deg, bsum);
  k_scanbsum<<<1, 512, 0, stream>>>(bsum, boff);
  k_ptr<<<NBLK, 256, 0, stream>>>(deg, boff, rowptr, cursor);
  scatter_kernel<<<6250, 256, 0, stream>>>(src, dst, cursor, csr);

  gemm_kernel<128><<<1024, 256, 0, stream>>>(xb, WT1, XWs, XWn);
  agg_epi_kernel<<<25000, 256, 0, stream>>>(XWs, XWn, rowptr, csr, b1s, b1n, h1);
  gemm_kernel<256><<<512, 256, 0, stream>>>(h1, WT2, XWs, XWn);
  agg_epi_kernel<<<25000, 256, 0, stream>>>(XWs, XWn, rowptr, csr, b2s, b2n, h2);
  fc_kernel<<<1563, 256, 0, stream>>>(h2, WFCT, bfc, out);
}

// Round 3
// 387.140 us; speedup vs baseline: 1.7732x; 1.3977x over previous
//
#include <hip/hip_runtime.h>
#include <hip/hip_bf16.h>

// GraphSAGE fwd on MI355X, v3.
// v2 -> v3: CSR build rewritten as two-level bucketing (no global per-edge
// atomics, no random 4B scatter): bucket_kernel groups edges into 512-node
// dst-buckets with per-block LDS ranking + one global atomic per
// bucket-per-block; csr_build sorts each bucket in LDS and streams the csr
// segment + rowptr slice out coalesced. Replaces hist/scan/ptr/scatter.
// Pipeline: prep | cvt | bucket | ebase | csr_build | gemm1 | agg1 | gemm2
// | agg2 | fc.

#define N_NODES 100000
#define N_EDGES 1600000
#define NBUCK   196      // ceil(N/512)
#define BCAP    12288    // slots per bucket (mean 8192, +45 sigma)
#define CHUNK   4096     // edges per bucket_kernel block

typedef unsigned short u16;
typedef __bf16 bf16x8 __attribute__((ext_vector_type(8)));
typedef float  f32x4  __attribute__((ext_vector_type(4)));

__device__ __forceinline__ u16 f2b(float f) {
  unsigned x = __builtin_bit_cast(unsigned, f);
  unsigned r = x + 0x7fffu + ((x >> 16) & 1u);
  return (u16)(r >> 16);
}
__device__ __forceinline__ float b2f(u16 u) {
  return __builtin_bit_cast(float, (unsigned)u << 16);
}
__device__ __forceinline__ bf16x8 ldfrag(const u16* p) {
  uint4 u = *reinterpret_cast<const uint4*>(p);
  return __builtin_bit_cast(bf16x8, u);
}

// ---------------- weight prep: bf16 + transpose to [col][k] ----------------
__global__ __launch_bounds__(256) void prep_weights(
    const float* __restrict__ w1s, const float* __restrict__ w1n,
    const float* __restrict__ w2s, const float* __restrict__ w2n,
    const float* __restrict__ wfc,
    u16* __restrict__ WT1, u16* __restrict__ WT2, u16* __restrict__ WFCT) {
  int i = blockIdx.x * 256 + threadIdx.x;
  if (i < 32768) {                       // WT1: [256 cols][128 k]
    int c = i >> 7, k = i & 127;
    float v = (c < 128) ? w1s[k * 128 + c] : w1n[k * 128 + (c - 128)];
    WT1[c * 128 + k] = f2b(v);
  } else if (i < 32768 + 65536) {        // WT2: [256 cols][256 k]
    int j = i - 32768;
    int c = j >> 8, k = j & 255;
    float v = (c < 128) ? w2s[k * 128 + c] : w2n[k * 128 + (c - 128)];
    WT2[c * 256 + k] = f2b(v);
  } else {                               // WFCT: [48 cols][256 k], cols 40..47 zero
    int j = i - 98304;
    int c = j >> 8, k = j & 255;
    float v = (c < 40) ? wfc[k * 40 + c] : 0.f;
    WFCT[c * 256 + k] = f2b(v);
  }
}

// ---------------- x -> bf16 ----------------
__global__ __launch_bounds__(256) void cvt_bf16(const float* __restrict__ x,
                                                u16* __restrict__ xb) {
  size_t i = ((size_t)blockIdx.x * 256 + threadIdx.x) * 8;
  float4 a = *reinterpret_cast<const float4*>(x + i);
  float4 b = *reinterpret_cast<const float4*>(x + i + 4);
  u16 o[8] = {f2b(a.x), f2b(a.y), f2b(a.z), f2b(a.w),
              f2b(b.x), f2b(b.y), f2b(b.z), f2b(b.w)};
  *reinterpret_cast<uint4*>(xb + i) = *reinterpret_cast<const uint4*>(o);
}

__device__ __forceinline__ int wave_incl_scan(int x, int lane) {
#pragma unroll
  for (int d = 1; d < 64; d <<= 1) {
    int n = __shfl_up(x, d, 64);
    if (lane >= d) x += n;
  }
  return x;
}

// ---------------- phase A: bucket edges by dst>>9 ----------------
// Per block: LDS histogram -> per-edge rank (LDS atomics), block scan,
// one global atomic per touched bucket to reserve, LDS-compact, stream out.
__global__ __launch_bounds__(256) void bucket_kernel(
    const int* __restrict__ src, const int* __restrict__ dst,
    int* __restrict__ cntg, uint2* __restrict__ pairBuf) {
  __shared__ unsigned hist[NBUCK];
  __shared__ unsigned gbase[NBUCK];
  __shared__ int sws[4];
  __shared__ uint2 stage[CHUNK];   // 32 KB
  __shared__ int tgt[CHUNK];       // 16 KB
  const int tid = threadIdx.x, lane = tid & 63, wid = tid >> 6;
  const int e0 = blockIdx.x * CHUNK;

  for (int i = tid; i < NBUCK; i += 256) hist[i] = 0u;
  __syncthreads();

  unsigned myD[16], myS[16];
  int myR[16], myB[16];
#pragma unroll
  for (int k = 0; k < 16; ++k) {
    int e = e0 + k * 256 + tid;
    if (e < N_EDGES) {
      unsigned d = (unsigned)dst[e];
      myD[k] = d;
      myS[k] = (unsigned)src[e];
      myB[k] = (int)(d >> 9);
      myR[k] = (int)atomicAdd(&hist[myB[k]], 1u);
    } else {
      myB[k] = -1;
    }
  }
  __syncthreads();

  int cnt = (tid < NBUCK) ? (int)hist[tid] : 0;
  int inc = wave_incl_scan(cnt, lane);
  if (lane == 63) sws[wid] = inc;
  __syncthreads();
  if (wid == 0) {
    int s = (lane < 4) ? sws[lane] : 0;
    s = wave_incl_scan(s, lane);
    if (lane < 4) sws[lane] = s;
  }
  __syncthreads();
  int excl = (wid ? sws[wid - 1] : 0) + inc - cnt;
  int gofs = 0;
  if (tid < NBUCK && cnt > 0) gofs = tid * BCAP + atomicAdd(&cntg[tid], cnt);
  __syncthreads();
  if (tid < NBUCK) {
    hist[tid] = (unsigned)excl;   // now local bucket offsets
    gbase[tid] = (unsigned)gofs;  // global reserved offsets
  }
  __syncthreads();

#pragma unroll
  for (int k = 0; k < 16; ++k) {
    if (myB[k] >= 0) {
      int slot = (int)hist[myB[k]] + myR[k];
      uint2 pr;
      pr.x = myD[k];
      pr.y = myS[k];
      stage[slot] = pr;
      tgt[slot] = (int)gbase[myB[k]] + myR[k];
    }
  }
  __syncthreads();
  int nvalid = N_EDGES - e0;
  if (nvalid > CHUNK) nvalid = CHUNK;
  for (int i = tid; i < nvalid; i += 256) pairBuf[tgt[i]] = stage[i];
}

// ---------------- per-bucket edge-count exclusive scan ----------------
__global__ __launch_bounds__(256) void k_ebase(const int* __restrict__ cntg,
                                               int* __restrict__ ebase) {
  const int tid = threadIdx.x, lane = tid & 63, wid = tid >> 6;
  __shared__ int sws[4];
  int v = (tid < NBUCK) ? cntg[tid] : 0;
  int inc = wave_incl_scan(v, lane);
  if (lane == 63) sws[wid] = inc;
  __syncthreads();
  if (wid == 0) {
    int s = (lane < 4) ? sws[lane] : 0;
    s = wave_incl_scan(s, lane);
    if (lane < 4) sws[lane] = s;
  }
  __syncthreads();
  if (tid < NBUCK) ebase[tid] = (wid ? sws[wid - 1] : 0) + inc - v;
}

// ---------------- phase B: build csr segment per bucket in LDS ----------------
__global__ __launch_bounds__(512) void csr_build(
    const uint2* __restrict__ pairBuf, const int* __restrict__ cntg,
    const int* __restrict__ ebase, int* __restrict__ rowptr,
    int* __restrict__ csr) {
  __shared__ int lcnt[512];
  __shared__ int lofs[512];
  __shared__ int sws[8];
  __shared__ int cstage[10240];    // 40 KB (bucket mean 8192, +22 sigma cap)
  const int b = blockIdx.x, tid = threadIdx.x;
  const int lane = tid & 63, wid = tid >> 6;
  int nb = cntg[b];
  if (nb > BCAP) nb = BCAP;
  if (nb > 10240) nb = 10240;
  const int eb = ebase[b];
  const uint2* pp = pairBuf + (size_t)b * BCAP;

  lcnt[tid] = 0;
  __syncthreads();
  for (int i = tid; i < nb; i += 512) atomicAdd(&lcnt[pp[i].x & 511], 1);
  __syncthreads();
  int v = lcnt[tid];
  int inc = wave_incl_scan(v, lane);
  if (lane == 63) sws[wid] = inc;
  __syncthreads();
  if (wid == 0) {
    int s = (lane < 8) ? sws[lane] : 0;
    s = wave_incl_scan(s, lane);
    if (lane < 8) sws[lane] = s;
  }
  __syncthreads();
  int excl = (wid ? sws[wid - 1] : 0) + inc - v;
  int node = b * 512 + tid;
  if (node <= N_NODES) rowptr[node] = eb + excl;
  lofs[tid] = excl;
  __syncthreads();
  for (int i = tid; i < nb; i += 512) {
    uint2 pr = pp[i];
    int pos = atomicAdd(&lofs[pr.x & 511], 1);
    cstage[pos] = (int)pr.y;
  }
  __syncthreads();
  for (int i = tid; i < nb; i += 512) csr[eb + i] = cstage[i];
}

// ---------------- persistent GEMM: C[s|n] = A[N,K] @ WT ----------------
// Block: 128 rows x 128 cols (one col-half). B staged once in LDS, XOR-swizzled
// so the 16-lane column-slice ds_read_b128 is bank-balanced. Persistent over
// row-chunks (stride gridDim/2). Wave: 2 row-tiles x 8 col-tiles.
template <int K>
__global__ __launch_bounds__(256) void gemm_kernel(
    const u16* __restrict__ A, const u16* __restrict__ WT,
    u16* __restrict__ Cs, u16* __restrict__ Cn) {
  constexpr int RB = K * 2;                      // LDS bytes per col-row
  constexpr int LOG2RB = (K == 128) ? 8 : 9;
  constexpr int KS = K / 32;
  __shared__ u16 lb[128 * K];                    // 32/64 KB

  const int tid = threadIdx.x;
  const int half = blockIdx.x & 1;
  u16* __restrict__ Cout = half ? Cn : Cs;

  // stage weight half -> LDS (swizzled)
  const u16* Wsrc = WT + (size_t)half * 128 * K;
  char* lbc = reinterpret_cast<char*>(lb);
#pragma unroll
  for (int i = tid; i < 128 * K / 8; i += 256) {
    uint4 v = *reinterpret_cast<const uint4*>(Wsrc + i * 8);
    int byte = i * 16;
    int swz = byte ^ (((byte >> LOG2RB) & 7) << 4);
    *reinterpret_cast<uint4*>(lbc + swz) = v;
  }
  __syncthreads();

  const int w = tid >> 6, lane = tid & 63;
  const int lrow = lane & 15, lk = lane >> 4;
  const int xr = (lrow & 7) << 4;                // lane-constant XOR
  const int stride = gridDim.x >> 1;

  for (int chunk = blockIdx.x >> 1; chunk * 128 < N_NODES; chunk += stride) {
    const int rbase = chunk * 128 + w * 32;
    // preload all A-fragments for this chunk (independent global loads)
    bf16x8 af[2][KS];
#pragma unroll
    for (int rt = 0; rt < 2; ++rt) {
      int r = rbase + rt * 16 + lrow;
      if (r >= N_NODES) r = N_NODES - 1;
      const u16* ap = A + (size_t)r * K + lk * 8;
#pragma unroll
      for (int ks = 0; ks < KS; ++ks) af[rt][ks] = ldfrag(ap + ks * 32);
    }
    f32x4 acc[2][8];
#pragma unroll
    for (int rt = 0; rt < 2; ++rt)
#pragma unroll
      for (int ct = 0; ct < 8; ++ct) acc[rt][ct] = f32x4{0.f, 0.f, 0.f, 0.f};

#pragma unroll
    for (int ks = 0; ks < KS; ++ks) {
#pragma unroll
      for (int ct = 0; ct < 8; ++ct) {
        int byte = (ct * 16 + lrow) * RB + ks * 64 + lk * 16;
        bf16x8 b = __builtin_bit_cast(
            bf16x8, *reinterpret_cast<const uint4*>(lbc + (byte ^ xr)));
        acc[0][ct] = __builtin_amdgcn_mfma_f32_16x16x32_bf16(af[0][ks], b, acc[0][ct], 0, 0, 0);
        acc[1][ct] = __builtin_amdgcn_mfma_f32_16x16x32_bf16(af[1][ks], b, acc[1][ct], 0, 0, 0);
      }
    }
    // store (D: row = 4*lk + j, col = ct*16 + lrow)
#pragma unroll
    for (int rt = 0; rt < 2; ++rt) {
#pragma unroll
      for (int j = 0; j < 4; ++j) {
        int r = rbase + rt * 16 + lk * 4 + j;
        if (r < N_NODES) {
          u16* cp = Cout + (size_t)r * 128 + lrow;
#pragma unroll
          for (int ct = 0; ct < 8; ++ct) cp[ct * 16] = f2b(acc[rt][ct][j]);
        }
      }
    }
  }
}

// ---------------- fused mean-agg + bias/relu/l2norm epilogue ----------------
__global__ __launch_bounds__(256) void agg_epi_kernel(
    const u16* __restrict__ Xs, const u16* __restrict__ Xn,
    const int* __restrict__ rowptr, const int* __restrict__ csr,
    const float* __restrict__ bs, const float* __restrict__ bn,
    u16* __restrict__ H) {
  int node = (int)((blockIdx.x * 256 + threadIdx.x) >> 6);
  int lane = threadIdx.x & 63;
  if (node >= N_NODES) return;
  int beg = rowptr[node], end = rowptr[node + 1];
  float a0 = 0.f, a1 = 0.f;
  int j = beg;
  for (; j + 3 < end; j += 4) {
    int s0 = csr[j], s1 = csr[j + 1], s2 = csr[j + 2], s3 = csr[j + 3];
    ushort2 u0 = *reinterpret_cast<const ushort2*>(Xn + (size_t)s0 * 128 + lane * 2);
    ushort2 u1 = *reinterpret_cast<const ushort2*>(Xn + (size_t)s1 * 128 + lane * 2);
    ushort2 u2 = *reinterpret_cast<const ushort2*>(Xn + (size_t)s2 * 128 + lane * 2);
    ushort2 u3 = *reinterpret_cast<const ushort2*>(Xn + (size_t)s3 * 128 + lane * 2);
    a0 += b2f(u0.x) + b2f(u1.x) + b2f(u2.x) + b2f(u3.x);
    a1 += b2f(u0.y) + b2f(u1.y) + b2f(u2.y) + b2f(u3.y);
  }
  for (; j < end; ++j) {
    ushort2 u = *reinterpret_cast<const ushort2*>(Xn + (size_t)csr[j] * 128 + lane * 2);
    a0 += b2f(u.x);
    a1 += b2f(u.y);
  }
  int d = end - beg;
  float inv = 1.f / (float)(d > 0 ? d : 1);
  ushort2 sv = *reinterpret_cast<const ushort2*>(Xs + (size_t)node * 128 + lane * 2);
  float2 bsv = *reinterpret_cast<const float2*>(bs + lane * 2);
  float2 bnv = *reinterpret_cast<const float2*>(bn + lane * 2);
  float s0 = fmaxf(b2f(sv.x) + bsv.x, 0.f);
  float s1 = fmaxf(b2f(sv.y) + bsv.y, 0.f);
  float n0 = fmaxf(a0 * inv + bnv.x, 0.f);
  float n1 = fmaxf(a1 * inv + bnv.y, 0.f);
  float ss = s0 * s0 + s1 * s1 + n0 * n0 + n1 * n1;
#pragma unroll
  for (int off = 1; off < 64; off <<= 1) ss += __shfl_xor(ss, off, 64);
  float sc = 1.f / fmaxf(sqrtf(ss), 1e-12f);
  ushort2 o0, o1;
  o0.x = f2b(s0 * sc);
  o0.y = f2b(s1 * sc);
  o1.x = f2b(n0 * sc);
  o1.y = f2b(n1 * sc);
  *reinterpret_cast<ushort2*>(H + (size_t)node * 256 + lane * 2) = o0;
  *reinterpret_cast<ushort2*>(H + (size_t)node * 256 + 128 + lane * 2) = o1;
}

// ---------------- FC head: out[N,40] = h2 @ wfc + bfc ----------------
__global__ __launch_bounds__(256) void fc_kernel(const u16* __restrict__ H2,
                                                 const u16* __restrict__ WFCT,
                                                 const float* __restrict__ bfc,
                                                 float* __restrict__ Out) {
  __shared__ u16 lb[48 * 256];   // 24 KB, swizzled RB=512
  char* lbc = reinterpret_cast<char*>(lb);
  const int tid = threadIdx.x;
#pragma unroll
  for (int i = tid; i < 48 * 256 / 8; i += 256) {
    uint4 v = *reinterpret_cast<const uint4*>(WFCT + i * 8);
    int byte = i * 16;
    int swz = byte ^ (((byte >> 9) & 7) << 4);
    *reinterpret_cast<uint4*>(lbc + swz) = v;
  }
  __syncthreads();
  const int w = tid >> 6, lane = tid & 63;
  const int lrow = lane & 15, lk = lane >> 4;
  const int xr = (lrow & 7) << 4;
  const int rbase = blockIdx.x * 64 + w * 16;

  bf16x8 af[8];
  {
    int r = rbase + lrow;
    if (r >= N_NODES) r = N_NODES - 1;
    const u16* ap = H2 + (size_t)r * 256 + lk * 8;
#pragma unroll
    for (int ks = 0; ks < 8; ++ks) af[ks] = ldfrag(ap + ks * 32);
  }
  f32x4 acc[3];
#pragma unroll
  for (int ct = 0; ct < 3; ++ct) acc[ct] = f32x4{0.f, 0.f, 0.f, 0.f};
#pragma unroll
  for (int ks = 0; ks < 8; ++ks) {
#pragma unroll
    for (int ct = 0; ct < 3; ++ct) {
      int byte = (ct * 16 + lrow) * 512 + ks * 64 + lk * 16;
      bf16x8 b = __builtin_bit_cast(
          bf16x8, *reinterpret_cast<const uint4*>(lbc + (byte ^ xr)));
      acc[ct] = __builtin_amdgcn_mfma_f32_16x16x32_bf16(af[ks], b, acc[ct], 0, 0, 0);
    }
  }
#pragma unroll
  for (int j = 0; j < 4; ++j) {
    int r = rbase + lk * 4 + j;
    if (r < N_NODES) {
#pragma unroll
      for (int ct = 0; ct < 3; ++ct) {
        int col = ct * 16 + lrow;
        if (col < 40) Out[(size_t)r * 40 + col] = acc[ct][j] + bfc[col];
      }
    }
  }
}

// ---------------- launch ----------------
extern "C" void kernel_launch(void* const* d_in, const int* in_sizes, int n_in,
                              void* d_out, int out_size, void* d_ws, size_t ws_size,
                              hipStream_t stream) {
  const float* x = (const float*)d_in[0];
  const int* src = (const int*)d_in[1];
  const int* dst = (const int*)d_in[2];
  const float* w1s = (const float*)d_in[3];
  const float* b1s = (const float*)d_in[4];
  const float* w1n = (const float*)d_in[5];
  const float* b1n = (const float*)d_in[6];
  const float* w2s = (const float*)d_in[7];
  const float* b2s = (const float*)d_in[8];
  const float* w2n = (const float*)d_in[9];
  const float* b2n = (const float*)d_in[10];
  const float* wfc = (const float*)d_in[11];
  const float* bfc = (const float*)d_in[12];
  float* out = (float*)d_out;

  char* p = (char*)d_ws;
  auto alloc = [&](size_t bytes) {
    char* r = p;
    p += (bytes + 255) & ~(size_t)255;
    return r;
  };
  u16* xb = (u16*)alloc((size_t)N_NODES * 128 * 2);    // 25.6 MB
  u16* XWs = (u16*)alloc((size_t)N_NODES * 128 * 2);   // 25.6 MB
  u16* XWn = (u16*)alloc((size_t)N_NODES * 128 * 2);   // 25.6 MB
  u16* h1 = (u16*)alloc((size_t)N_NODES * 256 * 2);    // 51.2 MB (h2 aliases)
  u16* WT1 = (u16*)alloc(32768 * 2);
  u16* WT2 = (u16*)alloc(65536 * 2);
  u16* WFCT = (u16*)alloc(12288 * 2);
  uint2* pairBuf = (uint2*)alloc((size_t)NBUCK * BCAP * 8);  // 19.3 MB
  int* cntg = (int*)alloc(NBUCK * 4);
  int* ebase = (int*)alloc(NBUCK * 4);
  int* rowptr = (int*)alloc((N_NODES + 1) * 4);
  int* csr = (int*)alloc((size_t)N_EDGES * 4);
  u16* h2 = h1;  // h1 dead after gemm2; agg2 writes h2 into the same buffer

  hipMemsetAsync(cntg, 0, NBUCK * 4, stream);
  prep_weights<<<432, 256, 0, stream>>>(w1s, w1n, w2s, w2n, wfc, WT1, WT2, WFCT);
  cvt_bf16<<<6250, 256, 0, stream>>>(x, xb);
  bucket_kernel<<<391, 256, 0, stream>>>(src, dst, cntg, pairBuf);
  k_ebase<<<1, 256, 0, stream>>>(cntg, ebase);
  csr_build<<<NBUCK, 512, 0, stream>>>(pairBuf, cntg, ebase, rowptr, csr);

  gemm_kernel<128><<<1024, 256, 0, stream>>>(xb, WT1, XWs, XWn);
  agg_epi_kernel<<<25000, 256, 0, stream>>>(XWs, XWn, rowptr, csr, b1s, b1n, h1);
  gemm_kernel<256><<<512, 256, 0, stream>>>(h1, WT2, XWs, XWn);
  agg_epi_kernel<<<25000, 256, 0, stream>>>(XWs, XWn, rowptr, csr, b2s, b2n, h2);
  fc_kernel<<<1563, 256, 0, stream>>>(h2, WFCT, bfc, out);
}

// Round 5
// 386.095 us; speedup vs baseline: 1.7780x; 1.0027x over previous
//
#include <hip/hip_runtime.h>
#include <hip/hip_bf16.h>

// GraphSAGE fwd on MI355X, v4 (resubmit — round-4 bench was an infra failure).
// v3 -> v4: (1) agg gather vectorized: 16 lanes/row x 4 rows in flight
// (uint4 loads) -> 4x fewer VMEM instrs + addr VALU per edge; (2) cvt_bf16
// deleted (gemm1 converts f32 A-fragments in-register, same rounding);
// (3) k_ebase merged into csr_build; pairBuf compressed to 4 B/edge.
// Pipeline: prep | bucket | csr_build | gemm1 | agg1 | gemm2 | agg2 | fc.

#define N_NODES 100000
#define N_EDGES 1600000
#define NBUCK   196      // ceil(N/512)
#define BCAP    12288    // slots per bucket (mean 8192, +45 sigma)
#define CHUNK   4096     // edges per bucket_kernel block

typedef unsigned short u16;
typedef unsigned int u32;
typedef __bf16 bf16x8 __attribute__((ext_vector_type(8)));
typedef float  f32x4  __attribute__((ext_vector_type(4)));

__device__ __forceinline__ u16 f2b(float f) {
  unsigned x = __builtin_bit_cast(unsigned, f);
  unsigned r = x + 0x7fffu + ((x >> 16) & 1u);
  return (u16)(r >> 16);
}
__device__ __forceinline__ float b2f(u16 u) {
  return __builtin_bit_cast(float, (unsigned)u << 16);
}
__device__ __forceinline__ bf16x8 ldfrag(const u16* p) {
  uint4 u = *reinterpret_cast<const uint4*>(p);
  return __builtin_bit_cast(bf16x8, u);
}
__device__ __forceinline__ void unpack8(uint4 u, float* f) {
  f[0] = __builtin_bit_cast(float, u.x << 16);
  f[1] = __builtin_bit_cast(float, u.x & 0xffff0000u);
  f[2] = __builtin_bit_cast(float, u.y << 16);
  f[3] = __builtin_bit_cast(float, u.y & 0xffff0000u);
  f[4] = __builtin_bit_cast(float, u.z << 16);
  f[5] = __builtin_bit_cast(float, u.z & 0xffff0000u);
  f[6] = __builtin_bit_cast(float, u.w << 16);
  f[7] = __builtin_bit_cast(float, u.w & 0xffff0000u);
}
__device__ __forceinline__ uint4 pack8(const float* f) {
  uint4 u;
  u.x = (u32)f2b(f[0]) | ((u32)f2b(f[1]) << 16);
  u.y = (u32)f2b(f[2]) | ((u32)f2b(f[3]) << 16);
  u.z = (u32)f2b(f[4]) | ((u32)f2b(f[5]) << 16);
  u.w = (u32)f2b(f[6]) | ((u32)f2b(f[7]) << 16);
  return u;
}

// ---------------- weight prep: bf16 + transpose to [col][k] ----------------
__global__ __launch_bounds__(256) void prep_weights(
    const float* __restrict__ w1s, const float* __restrict__ w1n,
    const float* __restrict__ w2s, const float* __restrict__ w2n,
    const float* __restrict__ wfc,
    u16* __restrict__ WT1, u16* __restrict__ WT2, u16* __restrict__ WFCT) {
  int i = blockIdx.x * 256 + threadIdx.x;
  if (i < 32768) {                       // WT1: [256 cols][128 k]
    int c = i >> 7, k = i & 127;
    float v = (c < 128) ? w1s[k * 128 + c] : w1n[k * 128 + (c - 128)];
    WT1[c * 128 + k] = f2b(v);
  } else if (i < 32768 + 65536) {        // WT2: [256 cols][256 k]
    int j = i - 32768;
    int c = j >> 8, k = j & 255;
    float v = (c < 128) ? w2s[k * 128 + c] : w2n[k * 128 + (c - 128)];
    WT2[c * 256 + k] = f2b(v);
  } else {                               // WFCT: [48 cols][256 k], cols 40..47 zero
    int j = i - 98304;
    int c = j >> 8, k = j & 255;
    float v = (c < 40) ? wfc[k * 40 + c] : 0.f;
    WFCT[c * 256 + k] = f2b(v);
  }
}

__device__ __forceinline__ int wave_incl_scan(int x, int lane) {
#pragma unroll
  for (int d = 1; d < 64; d <<= 1) {
    int n = __shfl_up(x, d, 64);
    if (lane >= d) x += n;
  }
  return x;
}

// ---------------- phase A: bucket edges by dst>>9 ----------------
// Per block: LDS histogram -> per-edge rank (LDS atomics), block scan,
// one global atomic per touched bucket to reserve, LDS-compact, stream out.
// Payload: (dst&511)<<17 | src  (src < 2^17).
__global__ __launch_bounds__(256) void bucket_kernel(
    const int* __restrict__ src, const int* __restrict__ dst,
    int* __restrict__ cntg, u32* __restrict__ pairBuf) {
  __shared__ unsigned hist[NBUCK];
  __shared__ unsigned gbase[NBUCK];
  __shared__ int sws[4];
  __shared__ u32 stage[CHUNK];     // 16 KB
  __shared__ int tgt[CHUNK];       // 16 KB
  const int tid = threadIdx.x, lane = tid & 63, wid = tid >> 6;
  const int e0 = blockIdx.x * CHUNK;

  for (int i = tid; i < NBUCK; i += 256) hist[i] = 0u;
  __syncthreads();

  u32 myW[16];
  int myR[16], myB[16];
#pragma unroll
  for (int k = 0; k < 16; ++k) {
    int e = e0 + k * 256 + tid;
    if (e < N_EDGES) {
      unsigned d = (unsigned)dst[e];
      myW[k] = ((d & 511u) << 17) | (unsigned)src[e];
      myB[k] = (int)(d >> 9);
      myR[k] = (int)atomicAdd(&hist[myB[k]], 1u);
    } else {
      myB[k] = -1;
    }
  }
  __syncthreads();

  int cnt = (tid < NBUCK) ? (int)hist[tid] : 0;
  int inc = wave_incl_scan(cnt, lane);
  if (lane == 63) sws[wid] = inc;
  __syncthreads();
  if (wid == 0) {
    int s = (lane < 4) ? sws[lane] : 0;
    s = wave_incl_scan(s, lane);
    if (lane < 4) sws[lane] = s;
  }
  __syncthreads();
  int excl = (wid ? sws[wid - 1] : 0) + inc - cnt;
  int gofs = 0;
  if (tid < NBUCK && cnt > 0) gofs = tid * BCAP + atomicAdd(&cntg[tid], cnt);
  __syncthreads();
  if (tid < NBUCK) {
    hist[tid] = (unsigned)excl;   // now local bucket offsets
    gbase[tid] = (unsigned)gofs;  // global reserved offsets
  }
  __syncthreads();

#pragma unroll
  for (int k = 0; k < 16; ++k) {
    if (myB[k] >= 0) {
      int slot = (int)hist[myB[k]] + myR[k];
      stage[slot] = myW[k];
      tgt[slot] = (int)gbase[myB[k]] + myR[k];
    }
  }
  __syncthreads();
  int nvalid = N_EDGES - e0;
  if (nvalid > CHUNK) nvalid = CHUNK;
  for (int i = tid; i < nvalid; i += 256) pairBuf[tgt[i]] = stage[i];
}

// ---------------- phase B: build csr segment per bucket in LDS ----------------
// Includes its own ebase computation (exclusive sum of cntg[0..b-1]).
__global__ __launch_bounds__(512) void csr_build(
    const u32* __restrict__ pairBuf, const int* __restrict__ cntg,
    int* __restrict__ rowptr, int* __restrict__ csr) {
  __shared__ int lcnt[512];
  __shared__ int lofs[512];
  __shared__ int sws[8];
  __shared__ int s_eb;
  __shared__ int cstage[10240];    // 40 KB (bucket mean 8192, +22 sigma cap)
  const int b = blockIdx.x, tid = threadIdx.x;
  const int lane = tid & 63, wid = tid >> 6;

  // eb = sum of cntg[0..b-1]
  {
    int v = (tid < b) ? cntg[tid] : 0;   // b <= 195 < 512
#pragma unroll
    for (int off = 1; off < 64; off <<= 1) v += __shfl_xor(v, off, 64);
    if (lane == 0) sws[wid] = v;
    __syncthreads();
    if (tid == 0) {
      int t = 0;
#pragma unroll
      for (int i = 0; i < 8; ++i) t += sws[i];
      s_eb = t;
    }
    __syncthreads();
  }
  const int eb = s_eb;
  int nb = cntg[b];
  if (nb > BCAP) nb = BCAP;
  if (nb > 10240) nb = 10240;
  const u32* pp = pairBuf + (size_t)b * BCAP;
  __syncthreads();

  lcnt[tid] = 0;
  __syncthreads();
  for (int i = tid; i < nb; i += 512) atomicAdd(&lcnt[(pp[i] >> 17) & 511], 1);
  __syncthreads();
  int v = lcnt[tid];
  int inc = wave_incl_scan(v, lane);
  if (lane == 63) sws[wid] = inc;
  __syncthreads();
  if (wid == 0) {
    int s = (lane < 8) ? sws[lane] : 0;
    s = wave_incl_scan(s, lane);
    if (lane < 8) sws[lane] = s;
  }
  __syncthreads();
  int excl = (wid ? sws[wid - 1] : 0) + inc - v;
  int node = b * 512 + tid;
  if (node <= N_NODES) rowptr[node] = eb + excl;
  lofs[tid] = excl;
  __syncthreads();
  for (int i = tid; i < nb; i += 512) {
    u32 pr = pp[i];
    int pos = atomicAdd(&lofs[(pr >> 17) & 511], 1);
    cstage[pos] = (int)(pr & 0x1FFFFu);
  }
  __syncthreads();
  for (int i = tid; i < nb; i += 512) csr[eb + i] = cstage[i];
}

// ---------------- persistent GEMM: C[s|n] = A[N,K] @ WT ----------------
// Block: 128 rows x 128 cols (one col-half). B staged once in LDS, XOR-swizzled.
// Persistent over row-chunks. Wave: 2 row-tiles x 8 col-tiles.
// AF32: A is f32, converted to bf16 in-register at fragment load (same
// rounding as a separate cvt pass).
template <int K, bool AF32>
__global__ __launch_bounds__(256) void gemm_kernel(
    const void* __restrict__ Av, const u16* __restrict__ WT,
    u16* __restrict__ Cs, u16* __restrict__ Cn) {
  constexpr int RB = K * 2;                      // LDS bytes per col-row
  constexpr int LOG2RB = (K == 128) ? 8 : 9;
  constexpr int KS = K / 32;
  __shared__ u16 lb[128 * K];                    // 32/64 KB

  const int tid = threadIdx.x;
  const int half = blockIdx.x & 1;
  u16* __restrict__ Cout = half ? Cn : Cs;

  // stage weight half -> LDS (swizzled)
  const u16* Wsrc = WT + (size_t)half * 128 * K;
  char* lbc = reinterpret_cast<char*>(lb);
#pragma unroll
  for (int i = tid; i < 128 * K / 8; i += 256) {
    uint4 v = *reinterpret_cast<const uint4*>(Wsrc + i * 8);
    int byte = i * 16;
    int swz = byte ^ (((byte >> LOG2RB) & 7) << 4);
    *reinterpret_cast<uint4*>(lbc + swz) = v;
  }
  __syncthreads();

  const int w = tid >> 6, lane = tid & 63;
  const int lrow = lane & 15, lk = lane >> 4;
  const int xr = (lrow & 7) << 4;                // lane-constant XOR
  const int stride = gridDim.x >> 1;

  for (int chunk = blockIdx.x >> 1; chunk * 128 < N_NODES; chunk += stride) {
    const int rbase = chunk * 128 + w * 32;
    // preload all A-fragments for this chunk (independent global loads)
    bf16x8 af[2][KS];
#pragma unroll
    for (int rt = 0; rt < 2; ++rt) {
      int r = rbase + rt * 16 + lrow;
      if (r >= N_NODES) r = N_NODES - 1;
      if constexpr (AF32) {
        const float* ap = (const float*)Av + (size_t)r * K + lk * 8;
#pragma unroll
        for (int ks = 0; ks < KS; ++ks) {
          float4 f0 = *reinterpret_cast<const float4*>(ap + ks * 32);
          float4 f1 = *reinterpret_cast<const float4*>(ap + ks * 32 + 4);
          float f[8] = {f0.x, f0.y, f0.z, f0.w, f1.x, f1.y, f1.z, f1.w};
          af[rt][ks] = __builtin_bit_cast(bf16x8, pack8(f));
        }
      } else {
        const u16* ap = (const u16*)Av + (size_t)r * K + lk * 8;
#pragma unroll
        for (int ks = 0; ks < KS; ++ks) af[rt][ks] = ldfrag(ap + ks * 32);
      }
    }
    f32x4 acc[2][8];
#pragma unroll
    for (int rt = 0; rt < 2; ++rt)
#pragma unroll
      for (int ct = 0; ct < 8; ++ct) acc[rt][ct] = f32x4{0.f, 0.f, 0.f, 0.f};

#pragma unroll
    for (int ks = 0; ks < KS; ++ks) {
#pragma unroll
      for (int ct = 0; ct < 8; ++ct) {
        int byte = (ct * 16 + lrow) * RB + ks * 64 + lk * 16;
        bf16x8 b = __builtin_bit_cast(
            bf16x8, *reinterpret_cast<const uint4*>(lbc + (byte ^ xr)));
        acc[0][ct] = __builtin_amdgcn_mfma_f32_16x16x32_bf16(af[0][ks], b, acc[0][ct], 0, 0, 0);
        acc[1][ct] = __builtin_amdgcn_mfma_f32_16x16x32_bf16(af[1][ks], b, acc[1][ct], 0, 0, 0);
      }
    }
    // store (D: row = 4*lk + j, col = ct*16 + lrow)
#pragma unroll
    for (int rt = 0; rt < 2; ++rt) {
#pragma unroll
      for (int j = 0; j < 4; ++j) {
        int r = rbase + rt * 16 + lk * 4 + j;
        if (r < N_NODES) {
          u16* cp = Cout + (size_t)r * 128 + lrow;
#pragma unroll
          for (int ct = 0; ct < 8; ++ct) cp[ct * 16] = f2b(acc[rt][ct][j]);
        }
      }
    }
  }
}

// ---------------- fused mean-agg + bias/relu/l2norm epilogue ----------------
// One wave per node, 16 lanes per gathered row (uint4 = 8 cols), 4 rows in
// flight (lane groups). Cross-group shfl combine, group-local ss reduce.
__global__ __launch_bounds__(256) void agg_epi_kernel(
    const u16* __restrict__ Xs, const u16* __restrict__ Xn,
    const int* __restrict__ rowptr, const int* __restrict__ csr,
    const float* __restrict__ bs, const float* __restrict__ bn,
    u16* __restrict__ H) {
  int node = (int)((blockIdx.x * 256 + threadIdx.x) >> 6);
  int lane = threadIdx.x & 63;
  if (node >= N_NODES) return;
  const int g = lane >> 4;    // edge sub-slot
  const int lc = lane & 15;   // column slot: cols lc*8 .. lc*8+7
  int beg = rowptr[node], end = rowptr[node + 1];

  float acc[8] = {0.f, 0.f, 0.f, 0.f, 0.f, 0.f, 0.f, 0.f};
  const u16* colbase = Xn + lc * 8;
  for (int j = beg; j < end; j += 4) {
    int e = j + g;
    int s = (e < end) ? csr[e] : 0;
    uint4 u = *reinterpret_cast<const uint4*>(colbase + (size_t)s * 128);
    if (e < end) {
      float f[8];
      unpack8(u, f);
#pragma unroll
      for (int i = 0; i < 8; ++i) acc[i] += f[i];
    }
  }
  // combine the 4 edge sub-slots
#pragma unroll
  for (int i = 0; i < 8; ++i) {
    acc[i] += __shfl_xor(acc[i], 32, 64);
    acc[i] += __shfl_xor(acc[i], 16, 64);
  }
  int d = end - beg;
  float inv = 1.f / (float)(d > 0 ? d : 1);

  uint4 sv4 = *reinterpret_cast<const uint4*>(Xs + (size_t)node * 128 + lc * 8);
  float sf[8];
  unpack8(sv4, sf);
  float4 b0 = *reinterpret_cast<const float4*>(bs + lc * 8);
  float4 b1 = *reinterpret_cast<const float4*>(bs + lc * 8 + 4);
  float4 c0 = *reinterpret_cast<const float4*>(bn + lc * 8);
  float4 c1 = *reinterpret_cast<const float4*>(bn + lc * 8 + 4);
  float bsv[8] = {b0.x, b0.y, b0.z, b0.w, b1.x, b1.y, b1.z, b1.w};
  float bnv[8] = {c0.x, c0.y, c0.z, c0.w, c1.x, c1.y, c1.z, c1.w};
  float nf[8];
  float ss = 0.f;
#pragma unroll
  for (int i = 0; i < 8; ++i) {
    sf[i] = fmaxf(sf[i] + bsv[i], 0.f);
    nf[i] = fmaxf(acc[i] * inv + bnv[i], 0.f);
    ss += sf[i] * sf[i] + nf[i] * nf[i];
  }
  // reduce over the 16 column-slots within this group
  ss += __shfl_xor(ss, 1, 64);
  ss += __shfl_xor(ss, 2, 64);
  ss += __shfl_xor(ss, 4, 64);
  ss += __shfl_xor(ss, 8, 64);
  float sc = 1.f / fmaxf(sqrtf(ss), 1e-12f);
#pragma unroll
  for (int i = 0; i < 8; ++i) {
    sf[i] *= sc;
    nf[i] *= sc;
  }
  if (g == 0) {
    *reinterpret_cast<uint4*>(H + (size_t)node * 256 + lc * 8) = pack8(sf);
  } else if (g == 1) {
    *reinterpret_cast<uint4*>(H + (size_t)node * 256 + 128 + lc * 8) = pack8(nf);
  }
}

// ---------------- FC head: out[N,40] = h2 @ wfc + bfc ----------------
__global__ __launch_bounds__(256) void fc_kernel(const u16* __restrict__ H2,
                                                 const u16* __restrict__ WFCT,
                                                 const float* __restrict__ bfc,
                                                 float* __restrict__ Out) {
  __shared__ u16 lb[48 * 256];   // 24 KB, swizzled RB=512
  char* lbc = reinterpret_cast<char*>(lb);
  const int tid = threadIdx.x;
#pragma unroll
  for (int i = tid; i < 48 * 256 / 8; i += 256) {
    uint4 v = *reinterpret_cast<const uint4*>(WFCT + i * 8);
    int byte = i * 16;
    int swz = byte ^ (((byte >> 9) & 7) << 4);
    *reinterpret_cast<uint4*>(lbc + swz) = v;
  }
  __syncthreads();
  const int w = tid >> 6, lane = tid & 63;
  const int lrow = lane & 15, lk = lane >> 4;
  const int xr = (lrow & 7) << 4;
  const int rbase = blockIdx.x * 64 + w * 16;

  bf16x8 af[8];
  {
    int r = rbase + lrow;
    if (r >= N_NODES) r = N_NODES - 1;
    const u16* ap = H2 + (size_t)r * 256 + lk * 8;
#pragma unroll
    for (int ks = 0; ks < 8; ++ks) af[ks] = ldfrag(ap + ks * 32);
  }
  f32x4 acc[3];
#pragma unroll
  for (int ct = 0; ct < 3; ++ct) acc[ct] = f32x4{0.f, 0.f, 0.f, 0.f};
#pragma unroll
  for (int ks = 0; ks < 8; ++ks) {
#pragma unroll
    for (int ct = 0; ct < 3; ++ct) {
      int byte = (ct * 16 + lrow) * 512 + ks * 64 + lk * 16;
      bf16x8 b = __builtin_bit_cast(
          bf16x8, *reinterpret_cast<const uint4*>(lbc + (byte ^ xr)));
      acc[ct] = __builtin_amdgcn_mfma_f32_16x16x32_bf16(af[ks], b, acc[ct], 0, 0, 0);
    }
  }
#pragma unroll
  for (int j = 0; j < 4; ++j) {
    int r = rbase + lk * 4 + j;
    if (r < N_NODES) {
#pragma unroll
      for (int ct = 0; ct < 3; ++ct) {
        int col = ct * 16 + lrow;
        if (col < 40) Out[(size_t)r * 40 + col] = acc[ct][j] + bfc[col];
      }
    }
  }
}

// ---------------- launch ----------------
extern "C" void kernel_launch(void* const* d_in, const int* in_sizes, int n_in,
                              void* d_out, int out_size, void* d_ws, size_t ws_size,
                              hipStream_t stream) {
  const float* x = (const float*)d_in[0];
  const int* src = (const int*)d_in[1];
  const int* dst = (const int*)d_in[2];
  const float* w1s = (const float*)d_in[3];
  const float* b1s = (const float*)d_in[4];
  const float* w1n = (const float*)d_in[5];
  const float* b1n = (const float*)d_in[6];
  const float* w2s = (const float*)d_in[7];
  const float* b2s = (const float*)d_in[8];
  const float* w2n = (const float*)d_in[9];
  const float* b2n = (const float*)d_in[10];
  const float* wfc = (const float*)d_in[11];
  const float* bfc = (const float*)d_in[12];
  float* out = (float*)d_out;

  char* p = (char*)d_ws;
  auto alloc = [&](size_t bytes) {
    char* r = p;
    p += (bytes + 255) & ~(size_t)255;
    return r;
  };
  u16* XWs = (u16*)alloc((size_t)N_NODES * 128 * 2);   // 25.6 MB
  u16* XWn = (u16*)alloc((size_t)N_NODES * 128 * 2);   // 25.6 MB
  u16* h1 = (u16*)alloc((size_t)N_NODES * 256 * 2);    // 51.2 MB (h2 aliases)
  u16* WT1 = (u16*)alloc(32768 * 2);
  u16* WT2 = (u16*)alloc(65536 * 2);
  u16* WFCT = (u16*)alloc(12288 * 2);
  u32* pairBuf = (u32*)alloc((size_t)NBUCK * BCAP * 4);  // 9.6 MB
  int* cntg = (int*)alloc(NBUCK * 4);
  int* rowptr = (int*)alloc((N_NODES + 1) * 4);
  int* csr = (int*)alloc((size_t)N_EDGES * 4);
  u16* h2 = h1;  // h1 dead after gemm2; agg2 writes h2 into the same buffer

  hipMemsetAsync(cntg, 0, NBUCK * 4, stream);
  prep_weights<<<432, 256, 0, stream>>>(w1s, w1n, w2s, w2n, wfc, WT1, WT2, WFCT);
  bucket_kernel<<<391, 256, 0, stream>>>(src, dst, cntg, pairBuf);
  csr_build<<<NBUCK, 512, 0, stream>>>(pairBuf, cntg, rowptr, csr);

  gemm_kernel<128, true><<<1024, 256, 0, stream>>>(x, WT1, XWs, XWn);
  agg_epi_kernel<<<25000, 256, 0, stream>>>(XWs, XWn, rowptr, csr, b1s, b1n, h1);
  gemm_kernel<256, false><<<512, 256, 0, stream>>>(h1, WT2, XWs, XWn);
  agg_epi_kernel<<<25000, 256, 0, stream>>>(XWs, XWn, rowptr, csr, b2s, b2n, h2);
  fc_kernel<<<1563, 256, 0, stream>>>(h2, WFCT, bfc, out);
}

// Round 6
// 359.864 us; speedup vs baseline: 1.9076x; 1.0729x over previous
//
#include <hip/hip_runtime.h>
#include <hip/hip_bf16.h>

// GraphSAGE fwd on MI355X, v5.
// v4 -> v5 (v4 result: agg is memory-path-bound; attack the rest):
//  - gemm kernels: 512-thr blocks compute all 256 cols; A read ONCE per chunk
//    (gemm1: full WT1 in 64KB LDS; gemm2: two 64KB halves staged sequentially,
//    A-frags held in regs). Halves gemm A traffic.
//  - fc fused into agg2 (agg_fc): 32 nodes/block -> LDS tile -> MFMA vs
//    LDS-staged WFCT -> direct out. Kills h2 write + fc read + 1 dispatch.
//  - CSR padded to x8 per node with sentinel row N (zeroed); fixed per-bucket
//    regions (no cross-bucket scan); agg loop branch-free, 2 gathers in flight.
//  - memset folded into prep_weights. 7 dispatches total.

#define N_NODES 100000
#define N_EDGES 1600000
#define NBUCK   196      // ceil(N/512)
#define BCAP    12288    // raw slots per bucket (mean 8163, +45 sigma)
#define PB_CAP  14336    // padded csr region per bucket
#define CHUNK   4096     // edges per bucket_kernel block

typedef unsigned short u16;
typedef unsigned int u32;
typedef __bf16 bf16x8 __attribute__((ext_vector_type(8)));
typedef float  f32x4  __attribute__((ext_vector_type(4)));

__device__ __forceinline__ u16 f2b(float f) {
  unsigned x = __builtin_bit_cast(unsigned, f);
  unsigned r = x + 0x7fffu + ((x >> 16) & 1u);
  return (u16)(r >> 16);
}
__device__ __forceinline__ bf16x8 ldfrag(const u16* p) {
  uint4 u = *reinterpret_cast<const uint4*>(p);
  return __builtin_bit_cast(bf16x8, u);
}
__device__ __forceinline__ void unpack8(uint4 u, float* f) {
  f[0] = __builtin_bit_cast(float, u.x << 16);
  f[1] = __builtin_bit_cast(float, u.x & 0xffff0000u);
  f[2] = __builtin_bit_cast(float, u.y << 16);
  f[3] = __builtin_bit_cast(float, u.y & 0xffff0000u);
  f[4] = __builtin_bit_cast(float, u.z << 16);
  f[5] = __builtin_bit_cast(float, u.z & 0xffff0000u);
  f[6] = __builtin_bit_cast(float, u.w << 16);
  f[7] = __builtin_bit_cast(float, u.w & 0xffff0000u);
}
__device__ __forceinline__ uint4 pack8(const float* f) {
  uint4 u;
  u.x = (u32)f2b(f[0]) | ((u32)f2b(f[1]) << 16);
  u.y = (u32)f2b(f[2]) | ((u32)f2b(f[3]) << 16);
  u.z = (u32)f2b(f[4]) | ((u32)f2b(f[5]) << 16);
  u.w = (u32)f2b(f[6]) | ((u32)f2b(f[7]) << 16);
  return u;
}

// ---------------- weight prep + cntg zero + sentinel row zero ----------------
__global__ __launch_bounds__(256) void prep_weights(
    const float* __restrict__ w1s, const float* __restrict__ w1n,
    const float* __restrict__ w2s, const float* __restrict__ w2n,
    const float* __restrict__ wfc,
    u16* __restrict__ WT1, u16* __restrict__ WT2, u16* __restrict__ WFCT,
    int* __restrict__ cntg, u16* __restrict__ XWn) {
  int i = blockIdx.x * 256 + threadIdx.x;
  if (i < 32768) {                       // WT1: [256 cols][128 k]
    int c = i >> 7, k = i & 127;
    float v = (c < 128) ? w1s[k * 128 + c] : w1n[k * 128 + (c - 128)];
    WT1[c * 128 + k] = f2b(v);
  } else if (i < 32768 + 65536) {        // WT2: [256 cols][256 k]
    int j = i - 32768;
    int c = j >> 8, k = j & 255;
    float v = (c < 128) ? w2s[k * 128 + c] : w2n[k * 128 + (c - 128)];
    WT2[c * 256 + k] = f2b(v);
  } else if (i < 98304 + 12288) {        // WFCT: [48 cols][256 k], 40..47 zero
    int j = i - 98304;
    int c = j >> 8, k = j & 255;
    float v = (c < 40) ? wfc[k * 40 + c] : 0.f;
    WFCT[c * 256 + k] = f2b(v);
  } else {                               // housekeeping block
    int t = threadIdx.x;
    if (t < NBUCK) cntg[t] = 0;
    if (t >= 128 && t < 256) XWn[(size_t)N_NODES * 128 + (t - 128)] = 0;
  }
}

__device__ __forceinline__ int wave_incl_scan(int x, int lane) {
#pragma unroll
  for (int d = 1; d < 64; d <<= 1) {
    int n = __shfl_up(x, d, 64);
    if (lane >= d) x += n;
  }
  return x;
}

// ---------------- phase A: bucket edges by dst>>9 ----------------
__global__ __launch_bounds__(256) void bucket_kernel(
    const int* __restrict__ src, const int* __restrict__ dst,
    int* __restrict__ cntg, u32* __restrict__ pairBuf) {
  __shared__ unsigned hist[NBUCK];
  __shared__ unsigned gbase[NBUCK];
  __shared__ int sws[4];
  __shared__ u32 stage[CHUNK];     // 16 KB
  __shared__ int tgt[CHUNK];       // 16 KB
  const int tid = threadIdx.x, lane = tid & 63, wid = tid >> 6;
  const int e0 = blockIdx.x * CHUNK;

  for (int i = tid; i < NBUCK; i += 256) hist[i] = 0u;
  __syncthreads();

  u32 myW[16];
  int myR[16], myB[16];
#pragma unroll
  for (int k = 0; k < 16; ++k) {
    int e = e0 + k * 256 + tid;
    if (e < N_EDGES) {
      unsigned d = (unsigned)dst[e];
      myW[k] = ((d & 511u) << 17) | (unsigned)src[e];
      myB[k] = (int)(d >> 9);
      myR[k] = (int)atomicAdd(&hist[myB[k]], 1u);
    } else {
      myB[k] = -1;
    }
  }
  __syncthreads();

  int cnt = (tid < NBUCK) ? (int)hist[tid] : 0;
  int inc = wave_incl_scan(cnt, lane);
  if (lane == 63) sws[wid] = inc;
  __syncthreads();
  if (wid == 0) {
    int s = (lane < 4) ? sws[lane] : 0;
    s = wave_incl_scan(s, lane);
    if (lane < 4) sws[lane] = s;
  }
  __syncthreads();
  int excl = (wid ? sws[wid - 1] : 0) + inc - cnt;
  int gofs = 0;
  if (tid < NBUCK && cnt > 0) gofs = tid * BCAP + atomicAdd(&cntg[tid], cnt);
  __syncthreads();
  if (tid < NBUCK) {
    hist[tid] = (unsigned)excl;   // local bucket offsets
    gbase[tid] = (unsigned)gofs;  // global reserved offsets
  }
  __syncthreads();

#pragma unroll
  for (int k = 0; k < 16; ++k) {
    if (myB[k] >= 0) {
      int slot = (int)hist[myB[k]] + myR[k];
      stage[slot] = myW[k];
      tgt[slot] = (int)gbase[myB[k]] + myR[k];
    }
  }
  __syncthreads();
  int nvalid = N_EDGES - e0;
  if (nvalid > CHUNK) nvalid = CHUNK;
  for (int i = tid; i < nvalid; i += 256) pairBuf[tgt[i]] = stage[i];
}

// ---------------- phase B: padded csr segment per bucket ----------------
// Fixed region csr[b*PB_CAP ...]. Each node's list padded to x8 with sentinel
// src = N_NODES (a zeroed row). rowptr = padded start; degA = true degree.
__global__ __launch_bounds__(512) void csr_build(
    const u32* __restrict__ pairBuf, const int* __restrict__ cntg,
    int* __restrict__ rowptr, int* __restrict__ degA, int* __restrict__ csr) {
  __shared__ int lcnt[512];
  __shared__ int lofs[512];
  __shared__ int sws[8];
  __shared__ int cstage[PB_CAP];   // 56 KB
  const int b = blockIdx.x, tid = threadIdx.x;
  const int lane = tid & 63, wid = tid >> 6;
  int nb = cntg[b];
  if (nb > BCAP) nb = BCAP;
  const u32* pp = pairBuf + (size_t)b * BCAP;

  lcnt[tid] = 0;
  __syncthreads();
  for (int i = tid; i < nb; i += 512) atomicAdd(&lcnt[(pp[i] >> 17) & 511], 1);
  __syncthreads();
  int dg = lcnt[tid];
  int pd = (dg + 7) & ~7;
  int inc = wave_incl_scan(pd, lane);
  if (lane == 63) sws[wid] = inc;
  __syncthreads();
  if (wid == 0) {
    int s = (lane < 8) ? sws[lane] : 0;
    s = wave_incl_scan(s, lane);
    if (lane < 8) sws[lane] = s;
  }
  __syncthreads();
  int excl = (wid ? sws[wid - 1] : 0) + inc - pd;
  int ptot = sws[7];
  int node = b * 512 + tid;
  if (node < N_NODES) {
    rowptr[node] = b * PB_CAP + excl;
    degA[node] = dg;
  }
  lofs[tid] = excl;
  __syncthreads();
  for (int i = tid; i < nb; i += 512) {
    u32 pr = pp[i];
    int pos = atomicAdd(&lofs[(pr >> 17) & 511], 1);
    if (pos < PB_CAP) cstage[pos] = (int)(pr & 0x1FFFFu);
  }
  __syncthreads();
  for (int k = excl + dg; k < excl + pd; ++k)
    if (k < PB_CAP) cstage[k] = N_NODES;  // sentinel pads
  __syncthreads();
  if (ptot > PB_CAP) ptot = PB_CAP;
  for (int i = tid; i < ptot; i += 512) csr[b * PB_CAP + i] = cstage[i];
}

// ---------------- shared aggregation helper (one wave, one node) ----------------
// Lane (g = lane>>4, lc = lane&15): returns biased/relu'd/l2-normalized
// sf[8] (self cols lc*8..) and nf[8] (neigh cols lc*8..), replicated over g.
__device__ __forceinline__ void agg_node(
    const u16* __restrict__ Xs, const u16* __restrict__ Xn,
    const int* __restrict__ rowptr, const int* __restrict__ degA,
    const int* __restrict__ csr, const float* __restrict__ bs,
    const float* __restrict__ bn, int node, int g, int lc,
    float* sf, float* nf) {
  int beg = rowptr[node], dg = degA[node];
  int cnt = (dg + 7) & ~7;
  float acc[8] = {0.f, 0.f, 0.f, 0.f, 0.f, 0.f, 0.f, 0.f};
  const u16* colbase = Xn + lc * 8;
  const int* cp = csr + beg;
  for (int j = 0; j < cnt; j += 8) {
    int s0 = cp[j + g];
    int s1 = cp[j + 4 + g];
    uint4 u0 = *reinterpret_cast<const uint4*>(colbase + (size_t)s0 * 128);
    uint4 u1 = *reinterpret_cast<const uint4*>(colbase + (size_t)s1 * 128);
    float f0[8], f1[8];
    unpack8(u0, f0);
    unpack8(u1, f1);
#pragma unroll
    for (int i = 0; i < 8; ++i) acc[i] += f0[i] + f1[i];
  }
#pragma unroll
  for (int i = 0; i < 8; ++i) {
    acc[i] += __shfl_xor(acc[i], 32, 64);
    acc[i] += __shfl_xor(acc[i], 16, 64);
  }
  float inv = 1.f / (float)(dg > 0 ? dg : 1);
  uint4 sv4 = *reinterpret_cast<const uint4*>(Xs + (size_t)node * 128 + lc * 8);
  unpack8(sv4, sf);
  float4 b0 = *reinterpret_cast<const float4*>(bs + lc * 8);
  float4 b1 = *reinterpret_cast<const float4*>(bs + lc * 8 + 4);
  float4 c0 = *reinterpret_cast<const float4*>(bn + lc * 8);
  float4 c1 = *reinterpret_cast<const float4*>(bn + lc * 8 + 4);
  float bsv[8] = {b0.x, b0.y, b0.z, b0.w, b1.x, b1.y, b1.z, b1.w};
  float bnv[8] = {c0.x, c0.y, c0.z, c0.w, c1.x, c1.y, c1.z, c1.w};
  float ss = 0.f;
#pragma unroll
  for (int i = 0; i < 8; ++i) {
    sf[i] = fmaxf(sf[i] + bsv[i], 0.f);
    nf[i] = fmaxf(acc[i] * inv + bnv[i], 0.f);
    ss += sf[i] * sf[i] + nf[i] * nf[i];
  }
  ss += __shfl_xor(ss, 1, 64);
  ss += __shfl_xor(ss, 2, 64);
  ss += __shfl_xor(ss, 4, 64);
  ss += __shfl_xor(ss, 8, 64);
  float sc = 1.f / fmaxf(sqrtf(ss), 1e-12f);
#pragma unroll
  for (int i = 0; i < 8; ++i) {
    sf[i] *= sc;
    nf[i] *= sc;
  }
}

// ---------------- agg1: mean-agg + epilogue, writes H [N,256] ----------------
__global__ __launch_bounds__(256) void agg_epi_kernel(
    const u16* __restrict__ Xs, const u16* __restrict__ Xn,
    const int* __restrict__ rowptr, const int* __restrict__ degA,
    const int* __restrict__ csr, const float* __restrict__ bs,
    const float* __restrict__ bn, u16* __restrict__ H) {
  int node = (int)((blockIdx.x * 256 + threadIdx.x) >> 6);
  int lane = threadIdx.x & 63;
  if (node >= N_NODES) return;
  const int g = lane >> 4, lc = lane & 15;
  float sf[8], nf[8];
  agg_node(Xs, Xn, rowptr, degA, csr, bs, bn, node, g, lc, sf, nf);
  if (g == 0) {
    *reinterpret_cast<uint4*>(H + (size_t)node * 256 + lc * 8) = pack8(sf);
  } else if (g == 1) {
    *reinterpret_cast<uint4*>(H + (size_t)node * 256 + 128 + lc * 8) = pack8(nf);
  }
}

// ---------------- agg2 + fused FC head ----------------
// 512 thr = 8 waves, 32 nodes/block. Each wave aggregates 4 nodes into an LDS
// tile, then the block does out[32,40] = tile @ wfc + bfc via MFMA and writes
// the final output directly (h2 never materialized).
__global__ __launch_bounds__(512) void agg_fc_kernel(
    const u16* __restrict__ Xs, const u16* __restrict__ Xn,
    const int* __restrict__ rowptr, const int* __restrict__ degA,
    const int* __restrict__ csr, const float* __restrict__ bs,
    const float* __restrict__ bn, const u16* __restrict__ WFCT,
    const float* __restrict__ bfc, float* __restrict__ Out) {
  __shared__ u16 hh[32][264];   // 16.9 KB (+8 pad: 2-way-max bank aliasing)
  __shared__ u16 wf[48][264];   // 25.3 KB
  const int tid = threadIdx.x, w = tid >> 6, lane = tid & 63;
  const int g = lane >> 4, lc = lane & 15;
  const int nb0 = blockIdx.x * 32;

  // stage WFCT [48][256] -> padded LDS
  for (int i = tid; i < 1536; i += 512) {
    int row = i >> 5, col = (i & 31) * 8;
    *reinterpret_cast<uint4*>(&wf[row][col]) =
        *reinterpret_cast<const uint4*>(WFCT + row * 256 + col);
  }

  // aggregate 4 nodes per wave into hh
  for (int t = 0; t < 4; ++t) {
    int r = w * 4 + t;
    int node = nb0 + r;
    if (node < N_NODES) {
      float sf[8], nf[8];
      agg_node(Xs, Xn, rowptr, degA, csr, bs, bn, node, g, lc, sf, nf);
      if (g == 0) {
        *reinterpret_cast<uint4*>(&hh[r][lc * 8]) = pack8(sf);
      } else if (g == 1) {
        *reinterpret_cast<uint4*>(&hh[r][128 + lc * 8]) = pack8(nf);
      }
    } else {
      uint4 z = {0u, 0u, 0u, 0u};
      if (g == 0) *reinterpret_cast<uint4*>(&hh[r][lc * 8]) = z;
      else if (g == 1) *reinterpret_cast<uint4*>(&hh[r][128 + lc * 8]) = z;
    }
  }
  __syncthreads();

  // fc: wave task (rt = w&1, cg = w>>1), cg<3 covers 48 cols
  const int rt = w & 1, cg = w >> 1;
  if (cg < 3) {
    const int lrow = lane & 15, lk = lane >> 4;
    f32x4 acc = {0.f, 0.f, 0.f, 0.f};
#pragma unroll
    for (int ks = 0; ks < 8; ++ks) {
      bf16x8 a = ldfrag(&hh[rt * 16 + lrow][ks * 32 + lk * 8]);
      bf16x8 b = ldfrag(&wf[cg * 16 + lrow][ks * 32 + lk * 8]);
      acc = __builtin_amdgcn_mfma_f32_16x16x32_bf16(a, b, acc, 0, 0, 0);
    }
#pragma unroll
    for (int j = 0; j < 4; ++j) {
      int row = nb0 + rt * 16 + lk * 4 + j;
      int col = cg * 16 + lrow;
      if (row < N_NODES && col < 40) Out[(size_t)row * 40 + col] = acc[j] + bfc[col];
    }
  }
}

// ---------------- gemm1: [Cs|Cn] = bf16(x_f32) @ WT1, all 256 cols ----------------
__global__ __launch_bounds__(512) void gemm1_kernel(
    const float* __restrict__ A, const u16* __restrict__ WT,
    u16* __restrict__ Cs, u16* __restrict__ Cn) {
  __shared__ u16 lb[256 * 128];   // 64 KB: [256 cols][128 k], swizzled RB=256
  char* lbc = reinterpret_cast<char*>(lb);
  const int tid = threadIdx.x;
  for (int i = tid; i < 4096; i += 512) {
    uint4 v = *reinterpret_cast<const uint4*>(WT + i * 8);
    int byte = i * 16;
    int swz = byte ^ (((byte >> 8) & 7) << 4);
    *reinterpret_cast<uint4*>(lbc + swz) = v;
  }

  const int w = tid >> 6, lane = tid & 63;
  const int lrow = lane & 15, lk = lane >> 4;
  const int xr = (lrow & 7) << 4;
  const int rbase = blockIdx.x * 128 + w * 16;

  // A-frags: f32 -> bf16 in-register
  bf16x8 af[4];
  {
    int r = rbase + lrow;
    if (r >= N_NODES) r = N_NODES - 1;
    const float* ap = A + (size_t)r * 128 + lk * 8;
#pragma unroll
    for (int ks = 0; ks < 4; ++ks) {
      float4 f0 = *reinterpret_cast<const float4*>(ap + ks * 32);
      float4 f1 = *reinterpret_cast<const float4*>(ap + ks * 32 + 4);
      float f[8] = {f0.x, f0.y, f0.z, f0.w, f1.x, f1.y, f1.z, f1.w};
      af[ks] = __builtin_bit_cast(bf16x8, pack8(f));
    }
  }
  __syncthreads();

  f32x4 acc[16];
#pragma unroll
  for (int ct = 0; ct < 16; ++ct) acc[ct] = f32x4{0.f, 0.f, 0.f, 0.f};
#pragma unroll
  for (int ks = 0; ks < 4; ++ks) {
#pragma unroll
    for (int ct = 0; ct < 16; ++ct) {
      int byte = (ct * 16 + lrow) * 256 + ks * 64 + lk * 16;
      bf16x8 b = __builtin_bit_cast(
          bf16x8, *reinterpret_cast<const uint4*>(lbc + (byte ^ xr)));
      acc[ct] = __builtin_amdgcn_mfma_f32_16x16x32_bf16(af[ks], b, acc[ct], 0, 0, 0);
    }
  }
#pragma unroll
  for (int j = 0; j < 4; ++j) {
    int r = rbase + lk * 4 + j;
    if (r < N_NODES) {
      u16* cs = Cs + (size_t)r * 128 + lrow;
      u16* cn = Cn + (size_t)r * 128 + lrow;
#pragma unroll
      for (int ct = 0; ct < 8; ++ct) cs[ct * 16] = f2b(acc[ct][j]);
#pragma unroll
      for (int ct = 0; ct < 8; ++ct) cn[ct * 16] = f2b(acc[8 + ct][j]);
    }
  }
}

// ---------------- gemm2: [Cs|Cn] = H1 @ WT2, halves staged sequentially ----------------
__global__ __launch_bounds__(512) void gemm2_kernel(
    const u16* __restrict__ A, const u16* __restrict__ WT,
    u16* __restrict__ Cs, u16* __restrict__ Cn) {
  __shared__ u16 lb[128 * 256];   // 64 KB: [128 cols][256 k], swizzled RB=512
  char* lbc = reinterpret_cast<char*>(lb);
  const int tid = threadIdx.x;
  const int w = tid >> 6, lane = tid & 63;
  const int lrow = lane & 15, lk = lane >> 4;
  const int xr = (lrow & 7) << 4;
  const int rbase = blockIdx.x * 128 + w * 16;

  // A-frags held across both halves
  bf16x8 af[8];
  {
    int r = rbase + lrow;
    if (r >= N_NODES) r = N_NODES - 1;
    const u16* ap = A + (size_t)r * 256 + lk * 8;
#pragma unroll
    for (int ks = 0; ks < 8; ++ks) af[ks] = ldfrag(ap + ks * 32);
  }

#pragma unroll
  for (int half = 0; half < 2; ++half) {
    const u16* Wsrc = WT + (size_t)half * 128 * 256;
    for (int i = tid; i < 4096; i += 512) {
      uint4 v = *reinterpret_cast<const uint4*>(Wsrc + i * 8);
      int byte = i * 16;
      int swz = byte ^ (((byte >> 9) & 7) << 4);
      *reinterpret_cast<uint4*>(lbc + swz) = v;
    }
    __syncthreads();

    f32x4 acc[8];
#pragma unroll
    for (int ct = 0; ct < 8; ++ct) acc[ct] = f32x4{0.f, 0.f, 0.f, 0.f};
#pragma unroll
    for (int ks = 0; ks < 8; ++ks) {
#pragma unroll
      for (int ct = 0; ct < 8; ++ct) {
        int byte = (ct * 16 + lrow) * 512 + ks * 64 + lk * 16;
        bf16x8 b = __builtin_bit_cast(
            bf16x8, *reinterpret_cast<const uint4*>(lbc + (byte ^ xr)));
        acc[ct] = __builtin_amdgcn_mfma_f32_16x16x32_bf16(af[ks], b, acc[ct], 0, 0, 0);
      }
    }
    u16* __restrict__ Cout = half ? Cn : Cs;
#pragma unroll
    for (int j = 0; j < 4; ++j) {
      int r = rbase + lk * 4 + j;
      if (r < N_NODES) {
        u16* cp = Cout + (size_t)r * 128 + lrow;
#pragma unroll
        for (int ct = 0; ct < 8; ++ct) cp[ct * 16] = f2b(acc[ct][j]);
      }
    }
    __syncthreads();   // all waves done with lb before restage
  }
}

// ---------------- launch ----------------
extern "C" void kernel_launch(void* const* d_in, const int* in_sizes, int n_in,
                              void* d_out, int out_size, void* d_ws, size_t ws_size,
                              hipStream_t stream) {
  const float* x = (const float*)d_in[0];
  const int* src = (const int*)d_in[1];
  const int* dst = (const int*)d_in[2];
  const float* w1s = (const float*)d_in[3];
  const float* b1s = (const float*)d_in[4];
  const float* w1n = (const float*)d_in[5];
  const float* b1n = (const float*)d_in[6];
  const float* w2s = (const float*)d_in[7];
  const float* b2s = (const float*)d_in[8];
  const float* w2n = (const float*)d_in[9];
  const float* b2n = (const float*)d_in[10];
  const float* wfc = (const float*)d_in[11];
  const float* bfc = (const float*)d_in[12];
  float* out = (float*)d_out;

  char* p = (char*)d_ws;
  auto alloc = [&](size_t bytes) {
    char* r = p;
    p += (bytes + 255) & ~(size_t)255;
    return r;
  };
  u16* XWs = (u16*)alloc((size_t)N_NODES * 128 * 2);        // 25.6 MB
  u16* XWn = (u16*)alloc(((size_t)N_NODES + 1) * 128 * 2);  // 25.6 MB (+sentinel row)
  u16* h1 = (u16*)alloc((size_t)N_NODES * 256 * 2);         // 51.2 MB
  u16* WT1 = (u16*)alloc(32768 * 2);
  u16* WT2 = (u16*)alloc(65536 * 2);
  u16* WFCT = (u16*)alloc(12288 * 2);
  u32* pairBuf = (u32*)alloc((size_t)NBUCK * BCAP * 4);     // 9.6 MB
  int* cntg = (int*)alloc(NBUCK * 4);
  int* rowptr = (int*)alloc((size_t)N_NODES * 4);
  int* degA = (int*)alloc((size_t)N_NODES * 4);
  int* csr = (int*)alloc((size_t)NBUCK * PB_CAP * 4);       // 11.2 MB

  prep_weights<<<433, 256, 0, stream>>>(w1s, w1n, w2s, w2n, wfc, WT1, WT2, WFCT,
                                        cntg, XWn);
  bucket_kernel<<<391, 256, 0, stream>>>(src, dst, cntg, pairBuf);
  csr_build<<<NBUCK, 512, 0, stream>>>(pairBuf, cntg, rowptr, degA, csr);

  gemm1_kernel<<<782, 512, 0, stream>>>(x, WT1, XWs, XWn);
  agg_epi_kernel<<<25000, 256, 0, stream>>>(XWs, XWn, rowptr, degA, csr, b1s, b1n, h1);
  gemm2_kernel<<<782, 512, 0, stream>>>(h1, WT2, XWs, XWn);
  agg_fc_kernel<<<3125, 512, 0, stream>>>(XWs, XWn, rowptr, degA, csr, b2s, b2n,
                                          WFCT, bfc, out);
}